// Round 2
// baseline (2001.824 us; speedup 1.0000x reference)
//
#include <hip/hip_runtime.h>
#include <stdint.h>

#define NN 100000
#define EE 3200000
#define DD 128
#define KK 50000

using u32 = unsigned int;
using u64 = unsigned long long;

// f32 -> bf16(RNE) -> f32, matching the harness's bf16-quantized reference.
__device__ __forceinline__ float bq(float f) {
  u32 b = __float_as_uint(f);
  b += 0x7FFFu + ((b >> 16) & 1u);
  return __uint_as_float(b & 0xFFFF0000u);
}

// ---------------- degree histogram ----------------
__global__ void k_deg(const int* __restrict__ ei, u32* __restrict__ deg) {
  int e = blockIdx.x * blockDim.x + threadIdx.x;
  if (e < EE) atomicAdd(&deg[ei[EE + e]], 1u);
}

__global__ void k_dinv(const u32* __restrict__ deg, double* __restrict__ dinv) {
  int i = blockIdx.x * blockDim.x + threadIdx.x;
  if (i < NN) dinv[i] = 1.0 / sqrt((double)(deg[i] + 1u)); // +1 self-loop
}

// ---------------- CSR offsets: 3-kernel scan ----------------
#define IBLK 391

__global__ void k_scan1(const u32* __restrict__ deg, u32* __restrict__ bsum) {
  __shared__ u32 sh[256];
  int t = threadIdx.x; int i = blockIdx.x * 256 + t;
  u32 v = (i < NN) ? deg[i] : 0u;
  sh[t] = v; __syncthreads();
  for (int s = 128; s > 0; s >>= 1) { if (t < s) sh[t] += sh[t + s]; __syncthreads(); }
  if (t == 0) bsum[blockIdx.x] = sh[0];
}

__global__ void k_scan2(u32* __restrict__ bsum, int nb) { // 1 block, 512 thr, nb<=512
  __shared__ u32 buf[2][512];
  int t = threadIdx.x;
  u32 v = (t < nb) ? bsum[t] : 0u;
  int a = 0; buf[0][t] = v; __syncthreads();
  for (int s = 1; s < 512; s <<= 1) {
    buf[1 - a][t] = buf[a][t] + ((t >= s) ? buf[a][t - s] : 0u);
    a = 1 - a; __syncthreads();
  }
  if (t < nb) bsum[t] = buf[a][t] - v; // exclusive
}

__global__ void k_scan3(const u32* __restrict__ deg, const u32* __restrict__ bsum,
                        u32* __restrict__ offs, u32* __restrict__ cur) {
  __shared__ u32 buf[2][256];
  int t = threadIdx.x; int i = blockIdx.x * 256 + t;
  u32 v = (i < NN) ? deg[i] : 0u;
  int a = 0; buf[0][t] = v; __syncthreads();
  for (int s = 1; s < 256; s <<= 1) {
    buf[1 - a][t] = buf[a][t] + ((t >= s) ? buf[a][t - s] : 0u);
    a = 1 - a; __syncthreads();
  }
  if (i < NN) {
    u32 exc = buf[a][t] - v + bsum[blockIdx.x];
    offs[i] = exc; cur[i] = exc;
  }
}

__global__ void k_scatter(const int* __restrict__ ei, u32* __restrict__ cur,
                          int* __restrict__ csr) {
  int e = blockIdx.x * blockDim.x + threadIdx.x;
  if (e < EE) {
    int d = ei[EE + e];
    u32 p = atomicAdd(&cur[d], 1u);
    csr[p] = ei[e]; // store src
  }
}

// ---------------- h = x @ W (accumulate f64, store TW) ----------------
template <typename TW>
__global__ void k_gemm(const float* __restrict__ x, const float* __restrict__ w,
                       TW* __restrict__ hW) {
  __shared__ float Wl[DD * DD]; // 64 KiB
  int t = threadIdx.x;
  for (int i = t; i < DD * DD; i += 256) Wl[i] = w[i];
  __syncthreads();
  int base = blockIdx.x * 16;
  int c = t & 127, rh = t >> 7;
  for (int it = 0; it < 8; ++it) {
    int r = base + it * 2 + rh;
    if (r < NN) {
      const float* xr = x + (size_t)r * DD;
      double acc = 0.0;
      #pragma unroll
      for (int k = 0; k < DD; ++k) acc += (double)xr[k] * (double)Wl[k * DD + c];
      hW[(size_t)r * DD + c] = (TW)acc;
    }
  }
}

// ---- gather-aggregate + self-loop + bias + score + key + gate (wave/node) ----
template <typename TW>
__global__ void k_agg(const TW* __restrict__ hW, const double* __restrict__ dinv,
                      const u32* __restrict__ offs, const u32* __restrict__ deg,
                      const int* __restrict__ csr, const float* __restrict__ bias,
                      float* __restrict__ hc, u64* __restrict__ key,
                      double* __restrict__ gate) {
  int node = blockIdx.x * 4 + (threadIdx.x >> 6);
  int lane = threadIdx.x & 63;
  if (node >= NN) return;
  double di = dinv[node];
  double a0 = 0.0, a1 = 0.0;
  u32 o = offs[node], cnt = deg[node];
  for (u32 k = 0; k < cnt; ++k) {
    int s = csr[o + k];
    double nrm = dinv[s] * di;
    const TW* hr = hW + (size_t)s * DD;
    a0 += (double)hr[lane] * nrm;
    a1 += (double)hr[lane + 64] * nrm;
  }
  double di2 = di * di;
  const TW* hi = hW + (size_t)node * DD;
  a0 += (double)hi[lane] * di2 + (double)bias[lane];
  a1 += (double)hi[lane + 64] * di2 + (double)bias[lane + 64];
  hc[(size_t)node * DD + lane] = (float)a0;
  hc[(size_t)node * DD + lane + 64] = (float)a1;
  double ss = a0 * a0 + a1 * a1;
  #pragma unroll
  for (int off = 32; off > 0; off >>= 1) ss += __shfl_xor(ss, off);
  if (lane == 0) {
    double sc = sqrt(ss + 1e-12); // > 0 always
    u64 bits = (u64)__double_as_longlong(sc);
    // strict total order: low 17 bits = (0x1FFFF - node) => lower index wins ties
    key[node] = (bits & ~0x1FFFFull) | (u64)(0x1FFFF - node);
    gate[node] = tanh(sc);
  }
}

// ---------------- rank by counting (j-split for occupancy) ----------------
#define JSPL 8
#define JCH 12500

__global__ void k_rank(const u64* __restrict__ key, u32* __restrict__ rankc) {
  int ib = blockIdx.x % IBLK;
  int jc = blockIdx.x / IBLK;
  int i = ib * 256 + threadIdx.x;
  u64 ki = (i < NN) ? key[i] : ~0ull;
  int j0 = jc * JCH, j1 = j0 + JCH; if (j1 > NN) j1 = NN;
  u32 cnt = 0;
  #pragma unroll 4
  for (int j = j0; j < j1; ++j) cnt += (key[j] > ki) ? 1u : 0u;
  if (i < NN && cnt) atomicAdd(&rankc[i], cnt);
}

__global__ void k_pos(const u32* __restrict__ rankc, int* __restrict__ pos) {
  int i = blockIdx.x * blockDim.x + threadIdx.x;
  if (i < NN) { u32 r = rankc[i]; pos[i] = (r < KK) ? (int)r : -1; }
}

// ---------------- outputs (f32, bf16-RNE-quantized) ----------------
__global__ void k_xout(const float* __restrict__ hc, const double* __restrict__ gate,
                       const int* __restrict__ pos, float* __restrict__ outx) {
  int id = blockIdx.x * blockDim.x + threadIdx.x;
  if (id >= NN * DD) return;
  int i = id >> 7, d = id & 127;
  int p = pos[i];
  if (p < 0) return;
  float v = (float)((double)hc[(size_t)i * DD + d] * gate[i]);
  outx[(size_t)p * DD + d] = bq(v);
}

__global__ void k_edges(const int* __restrict__ ei, const int* __restrict__ pos,
                        float* __restrict__ osrc, float* __restrict__ odst,
                        float* __restrict__ omask) {
  int e = blockIdx.x * blockDim.x + threadIdx.x;
  if (e >= EE) return;
  int ns = pos[ei[e]];
  int nd = pos[ei[EE + e]];
  bool m = (ns >= 0) && (nd >= 0);
  osrc[e] = m ? bq((float)ns) : -1.0f;
  odst[e] = m ? bq((float)nd) : -1.0f;
  omask[e] = m ? 1.0f : 0.0f;
}

// ---------------- driver ----------------
template <typename TW>
static void run_all(const float* x, const int* ei, const float* w, const float* bias,
                    float* outx, char* ws, hipStream_t stream) {
  size_t off = 0;
  auto alloc = [&](size_t b) -> void* {
    void* p = ws + off; off += (b + 255) & ~(size_t)255; return p;
  };
  TW*     hW    = (TW*)alloc((size_t)NN * DD * sizeof(TW));
  float*  hc    = (float*)alloc((size_t)NN * DD * sizeof(float));
  double* dinv  = (double*)alloc((size_t)NN * 8);
  double* gate  = (double*)alloc((size_t)NN * 8);
  u64*    key   = (u64*)alloc((size_t)NN * 8);
  u32*    deg   = (u32*)alloc((size_t)NN * 4);
  u32*    offs  = (u32*)alloc((size_t)NN * 4);
  u32*    cur   = (u32*)alloc((size_t)NN * 4);
  int*    csr   = (int*)alloc((size_t)EE * 4);
  u32*    rankc = (u32*)alloc((size_t)NN * 4);
  int*    pos   = (int*)alloc((size_t)NN * 4);
  u32*    bsum  = (u32*)alloc(512 * 4);

  hipMemsetAsync(deg, 0, (size_t)NN * 4, stream);
  hipMemsetAsync(rankc, 0, (size_t)NN * 4, stream);

  k_deg<<<(EE + 255) / 256, 256, 0, stream>>>(ei, deg);
  k_dinv<<<(NN + 255) / 256, 256, 0, stream>>>(deg, dinv);
  k_scan1<<<IBLK, 256, 0, stream>>>(deg, bsum);
  k_scan2<<<1, 512, 0, stream>>>(bsum, IBLK);
  k_scan3<<<IBLK, 256, 0, stream>>>(deg, bsum, offs, cur);
  k_scatter<<<(EE + 255) / 256, 256, 0, stream>>>(ei, cur, csr);
  k_gemm<TW><<<(NN + 15) / 16, 256, 0, stream>>>(x, w, hW);
  k_agg<TW><<<(NN + 3) / 4, 256, 0, stream>>>(hW, dinv, offs, deg, csr, bias, hc, key, gate);
  k_rank<<<IBLK * JSPL, 256, 0, stream>>>(key, rankc);
  k_pos<<<(NN + 255) / 256, 256, 0, stream>>>(rankc, pos);
  k_xout<<<(NN * DD + 255) / 256, 256, 0, stream>>>(hc, gate, pos, outx);
  float* oei = outx + (size_t)KK * DD;
  k_edges<<<(EE + 255) / 256, 256, 0, stream>>>(ei, pos, oei, oei + EE, oei + 2 * (size_t)EE);
}

extern "C" void kernel_launch(void* const* d_in, const int* in_sizes, int n_in,
                              void* d_out, int out_size, void* d_ws, size_t ws_size,
                              hipStream_t stream) {
  const float* x    = (const float*)d_in[0];
  const int*   ei   = (const int*)d_in[1];
  const float* w    = (const float*)d_in[2];
  const float* bias = (const float*)d_in[3];
  float* outx = (float*)d_out;

  // f64-hW tier needs ~171 MB of workspace; f32-hW tier needs ~120 MB.
  if (ws_size >= (size_t)175000000)
    run_all<double>(x, ei, w, bias, outx, (char*)d_ws, stream);
  else
    run_all<float>(x, ei, w, bias, outx, (char*)d_ws, stream);
}

// Round 3
// 1315.061 us; speedup vs baseline: 1.5222x; 1.5222x over previous
//
#include <hip/hip_runtime.h>
#include <stdint.h>

#define NN 100000
#define EE 3200000
#define DD 128
#define KK 50000
#define NB 131072   // rank buckets (2^17)
#define SBLK 512    // NB / 256

using u32 = unsigned int;
using u64 = unsigned long long;

// f32 -> bf16(RNE) -> f32, matching the harness's bf16-quantized reference.
__device__ __forceinline__ float bq(float f) {
  u32 b = __float_as_uint(f);
  b += 0x7FFFu + ((b >> 16) & 1u);
  return __uint_as_float(b & 0xFFFF0000u);
}

// ---------------- degree histogram ----------------
__global__ void k_deg(const int* __restrict__ ei, u32* __restrict__ deg) {
  int e = blockIdx.x * blockDim.x + threadIdx.x;
  if (e < EE) atomicAdd(&deg[ei[EE + e]], 1u);
}

__global__ void k_dinv(const u32* __restrict__ deg, double* __restrict__ dinv) {
  int i = blockIdx.x * blockDim.x + threadIdx.x;
  if (i < NN) dinv[i] = 1.0 / sqrt((double)(deg[i] + 1u)); // +1 self-loop
}

// ---------------- CSR offsets: 3-kernel scan ----------------
#define IBLK 391

__global__ void k_scan1(const u32* __restrict__ deg, u32* __restrict__ bsum) {
  __shared__ u32 sh[256];
  int t = threadIdx.x; int i = blockIdx.x * 256 + t;
  u32 v = (i < NN) ? deg[i] : 0u;
  sh[t] = v; __syncthreads();
  for (int s = 128; s > 0; s >>= 1) { if (t < s) sh[t] += sh[t + s]; __syncthreads(); }
  if (t == 0) bsum[blockIdx.x] = sh[0];
}

__global__ void k_scan2(u32* __restrict__ bsum, int nb) { // 1 block, 512 thr, nb<=512
  __shared__ u32 buf[2][512];
  int t = threadIdx.x;
  u32 v = (t < nb) ? bsum[t] : 0u;
  int a = 0; buf[0][t] = v; __syncthreads();
  for (int s = 1; s < 512; s <<= 1) {
    buf[1 - a][t] = buf[a][t] + ((t >= s) ? buf[a][t - s] : 0u);
    a = 1 - a; __syncthreads();
  }
  if (t < nb) bsum[t] = buf[a][t] - v; // exclusive
}

__global__ void k_scan3(const u32* __restrict__ deg, const u32* __restrict__ bsum,
                        u32* __restrict__ offs, u32* __restrict__ cur) {
  __shared__ u32 buf[2][256];
  int t = threadIdx.x; int i = blockIdx.x * 256 + t;
  u32 v = (i < NN) ? deg[i] : 0u;
  int a = 0; buf[0][t] = v; __syncthreads();
  for (int s = 1; s < 256; s <<= 1) {
    buf[1 - a][t] = buf[a][t] + ((t >= s) ? buf[a][t - s] : 0u);
    a = 1 - a; __syncthreads();
  }
  if (i < NN) {
    u32 exc = buf[a][t] - v + bsum[blockIdx.x];
    offs[i] = exc; cur[i] = exc;
  }
}

__global__ void k_scatter(const int* __restrict__ ei, u32* __restrict__ cur,
                          int* __restrict__ csr) {
  int e = blockIdx.x * blockDim.x + threadIdx.x;
  if (e < EE) {
    int d = ei[EE + e];
    u32 p = atomicAdd(&cur[d], 1u);
    csr[p] = ei[e]; // store src
  }
}

// ---------------- h = x @ W (accumulate f64, store TW) ----------------
template <typename TW>
__global__ void k_gemm(const float* __restrict__ x, const float* __restrict__ w,
                       TW* __restrict__ hW) {
  __shared__ float Wl[DD * DD]; // 64 KiB
  int t = threadIdx.x;
  for (int i = t; i < DD * DD; i += 256) Wl[i] = w[i];
  __syncthreads();
  int base = blockIdx.x * 16;
  int c = t & 127, rh = t >> 7;
  for (int it = 0; it < 8; ++it) {
    int r = base + it * 2 + rh;
    if (r < NN) {
      const float* xr = x + (size_t)r * DD;
      double acc = 0.0;
      #pragma unroll
      for (int k = 0; k < DD; ++k) acc += (double)xr[k] * (double)Wl[k * DD + c];
      hW[(size_t)r * DD + c] = (TW)acc;
    }
  }
}

// ---- gather-aggregate + self-loop + bias + score + key + gate (wave/node) ----
template <typename TW>
__global__ void k_agg(const TW* __restrict__ hW, const double* __restrict__ dinv,
                      const u32* __restrict__ offs, const u32* __restrict__ deg,
                      const int* __restrict__ csr, const float* __restrict__ bias,
                      float* __restrict__ hc, u64* __restrict__ key,
                      double* __restrict__ gate) {
  int node = blockIdx.x * 4 + (threadIdx.x >> 6);
  int lane = threadIdx.x & 63;
  if (node >= NN) return;
  double di = dinv[node];
  double a0 = 0.0, a1 = 0.0;
  u32 o = offs[node], cnt = deg[node];
  for (u32 k = 0; k < cnt; ++k) {
    int s = csr[o + k];
    double nrm = dinv[s] * di;
    const TW* hr = hW + (size_t)s * DD;
    a0 += (double)hr[lane] * nrm;
    a1 += (double)hr[lane + 64] * nrm;
  }
  double di2 = di * di;
  const TW* hi = hW + (size_t)node * DD;
  a0 += (double)hi[lane] * di2 + (double)bias[lane];
  a1 += (double)hi[lane + 64] * di2 + (double)bias[lane + 64];
  hc[(size_t)node * DD + lane] = (float)a0;
  hc[(size_t)node * DD + lane + 64] = (float)a1;
  double ss = a0 * a0 + a1 * a1;
  #pragma unroll
  for (int off = 32; off > 0; off >>= 1) ss += __shfl_xor(ss, off);
  if (lane == 0) {
    double sc = sqrt(ss + 1e-12); // > 0 always
    u64 bits = (u64)__double_as_longlong(sc);
    // strict total order: low 17 bits = (0x1FFFF - node) => lower index wins ties
    key[node] = (bits & ~0x1FFFFull) | (u64)(0x1FFFF - node);
    gate[node] = tanh(sc);
  }
}

// ---------------- exact bucket-rank select ----------------
// meta[0]=kmin, meta[1]=kmax, meta[2]=shift
__global__ void k_minmax(const u64* __restrict__ key, u64* __restrict__ meta) {
  __shared__ u64 smn[256], smx[256];
  int t = threadIdx.x; int i = blockIdx.x * 256 + t;
  u64 v = (i < NN) ? key[i] : key[0];
  smn[t] = v; smx[t] = v; __syncthreads();
  for (int s = 128; s > 0; s >>= 1) {
    if (t < s) {
      if (smn[t + s] < smn[t]) smn[t] = smn[t + s];
      if (smx[t + s] > smx[t]) smx[t] = smx[t + s];
    }
    __syncthreads();
  }
  if (t == 0) { atomicMin(&meta[0], smn[0]); atomicMax(&meta[1], smx[0]); }
}

__global__ void k_shift(u64* __restrict__ meta) {
  u64 range = meta[1] - meta[0];
  int bits = 64 - __clzll(range | 1ull);
  meta[2] = (u64)(bits > 17 ? bits - 17 : 0);
}

__global__ void k_hist(const u64* __restrict__ key, const u64* __restrict__ meta,
                       u32* __restrict__ barr, u32* __restrict__ bcnt) {
  int i = blockIdx.x * blockDim.x + threadIdx.x;
  if (i >= NN) return;
  u32 b = (u32)((key[i] - meta[0]) >> meta[2]);
  barr[i] = b;
  atomicAdd(&bcnt[b], 1u);
}

// suffix scan over NB buckets (descending bucket order) via reversed prefix scan
__global__ void k_bscan1(const u32* __restrict__ bcnt, u32* __restrict__ bsum2) {
  __shared__ u32 sh[256];
  int t = threadIdx.x; int r = blockIdx.x * 256 + t;
  u32 v = bcnt[NB - 1 - r];
  sh[t] = v; __syncthreads();
  for (int s = 128; s > 0; s >>= 1) { if (t < s) sh[t] += sh[t + s]; __syncthreads(); }
  if (t == 0) bsum2[blockIdx.x] = sh[0];
}

// base[b] = #keys in buckets > b;  cur[b] = storage offset = NN - base - cnt
__global__ void k_bscan3(const u32* __restrict__ bcnt, const u32* __restrict__ bsum2,
                         u32* __restrict__ base, u32* __restrict__ bcur) {
  __shared__ u32 buf[2][256];
  int t = threadIdx.x; int r = blockIdx.x * 256 + t;
  int b = NB - 1 - r;
  u32 v = bcnt[b];
  int a = 0; buf[0][t] = v; __syncthreads();
  for (int s = 1; s < 256; s <<= 1) {
    buf[1 - a][t] = buf[a][t] + ((t >= s) ? buf[a][t - s] : 0u);
    a = 1 - a; __syncthreads();
  }
  u32 bs = buf[a][t] - v + bsum2[blockIdx.x]; // suffix-exclusive
  base[b] = bs;
  bcur[b] = NN - bs - v;
}

__global__ void k_bscatter(const u32* __restrict__ barr, u32* __restrict__ bcur,
                           u32* __restrict__ blist) {
  int i = blockIdx.x * blockDim.x + threadIdx.x;
  if (i >= NN) return;
  u32 p = atomicAdd(&bcur[barr[i]], 1u);
  blist[p] = (u32)i;
}

__global__ void k_rank2(const u64* __restrict__ key, const u32* __restrict__ barr,
                        const u32* __restrict__ bcnt, const u32* __restrict__ base,
                        const u32* __restrict__ blist, int* __restrict__ pos) {
  int i = blockIdx.x * blockDim.x + threadIdx.x;
  if (i >= NN) return;
  u32 b = barr[i];
  u64 ki = key[i];
  u32 bs = base[b], cnt = bcnt[b];
  u32 off = NN - bs - cnt;
  u32 gt = 0;
  for (u32 j = 0; j < cnt; ++j) gt += (key[blist[off + j]] > ki) ? 1u : 0u;
  u32 rank = bs + gt;
  pos[i] = (rank < KK) ? (int)rank : -1;
}

// ---------------- outputs (f32, bf16-RNE-quantized) ----------------
__global__ void k_xout(const float* __restrict__ hc, const double* __restrict__ gate,
                       const int* __restrict__ pos, float* __restrict__ outx) {
  int id = blockIdx.x * blockDim.x + threadIdx.x;
  if (id >= NN * DD) return;
  int i = id >> 7, d = id & 127;
  int p = pos[i];
  if (p < 0) return;
  float v = (float)((double)hc[(size_t)i * DD + d] * gate[i]);
  outx[(size_t)p * DD + d] = bq(v);
}

__global__ void k_edges(const int* __restrict__ ei, const int* __restrict__ pos,
                        float* __restrict__ osrc, float* __restrict__ odst,
                        float* __restrict__ omask) {
  int e = blockIdx.x * blockDim.x + threadIdx.x;
  if (e >= EE) return;
  int ns = pos[ei[e]];
  int nd = pos[ei[EE + e]];
  bool m = (ns >= 0) && (nd >= 0);
  osrc[e] = m ? bq((float)ns) : -1.0f;
  odst[e] = m ? bq((float)nd) : -1.0f;
  omask[e] = m ? 1.0f : 0.0f;
}

// ---------------- driver ----------------
template <typename TW>
static void run_all(const float* x, const int* ei, const float* w, const float* bias,
                    float* outx, char* ws, hipStream_t stream) {
  size_t off = 0;
  auto alloc = [&](size_t b) -> void* {
    void* p = ws + off; off += (b + 255) & ~(size_t)255; return p;
  };
  TW*     hW    = (TW*)alloc((size_t)NN * DD * sizeof(TW));
  float*  hc    = (float*)alloc((size_t)NN * DD * sizeof(float));
  double* dinv  = (double*)alloc((size_t)NN * 8);
  double* gate  = (double*)alloc((size_t)NN * 8);
  u64*    key   = (u64*)alloc((size_t)NN * 8);
  u32*    deg   = (u32*)alloc((size_t)NN * 4);
  u32*    offs  = (u32*)alloc((size_t)NN * 4);
  u32*    cur   = (u32*)alloc((size_t)NN * 4);
  int*    csr   = (int*)alloc((size_t)EE * 4);
  int*    pos   = (int*)alloc((size_t)NN * 4);
  u32*    bsum  = (u32*)alloc(512 * 4);
  u64*    meta  = (u64*)alloc(4 * 8);
  u32*    bcnt  = (u32*)alloc((size_t)NB * 4);
  u32*    base  = (u32*)alloc((size_t)NB * 4);
  u32*    bcur  = (u32*)alloc((size_t)NB * 4);
  u32*    bsum2 = (u32*)alloc(SBLK * 4);
  u32*    barr  = (u32*)alloc((size_t)NN * 4);
  u32*    blist = (u32*)alloc((size_t)NN * 4);

  hipMemsetAsync(deg, 0, (size_t)NN * 4, stream);
  hipMemsetAsync(bcnt, 0, (size_t)NB * 4, stream);
  hipMemsetAsync(meta, 0xFF, 8, stream);      // kmin = ~0
  hipMemsetAsync(meta + 1, 0x00, 8, stream);  // kmax = 0

  k_deg<<<(EE + 255) / 256, 256, 0, stream>>>(ei, deg);
  k_dinv<<<(NN + 255) / 256, 256, 0, stream>>>(deg, dinv);
  k_scan1<<<IBLK, 256, 0, stream>>>(deg, bsum);
  k_scan2<<<1, 512, 0, stream>>>(bsum, IBLK);
  k_scan3<<<IBLK, 256, 0, stream>>>(deg, bsum, offs, cur);
  k_scatter<<<(EE + 255) / 256, 256, 0, stream>>>(ei, cur, csr);
  k_gemm<TW><<<(NN + 15) / 16, 256, 0, stream>>>(x, w, hW);
  k_agg<TW><<<(NN + 3) / 4, 256, 0, stream>>>(hW, dinv, offs, deg, csr, bias, hc, key, gate);
  // exact bucket-rank select (provably identical to O(N^2) rank-by-counting)
  k_minmax<<<IBLK, 256, 0, stream>>>(key, meta);
  k_shift<<<1, 1, 0, stream>>>(meta);
  k_hist<<<(NN + 255) / 256, 256, 0, stream>>>(key, meta, barr, bcnt);
  k_bscan1<<<SBLK, 256, 0, stream>>>(bcnt, bsum2);
  k_scan2<<<1, 512, 0, stream>>>(bsum2, SBLK);
  k_bscan3<<<SBLK, 256, 0, stream>>>(bcnt, bsum2, base, bcur);
  k_bscatter<<<(NN + 255) / 256, 256, 0, stream>>>(barr, bcur, blist);
  k_rank2<<<(NN + 255) / 256, 256, 0, stream>>>(key, barr, bcnt, base, blist, pos);
  k_xout<<<(NN * DD + 255) / 256, 256, 0, stream>>>(hc, gate, pos, outx);
  float* oei = outx + (size_t)KK * DD;
  k_edges<<<(EE + 255) / 256, 256, 0, stream>>>(ei, pos, oei, oei + EE, oei + 2 * (size_t)EE);
}

extern "C" void kernel_launch(void* const* d_in, const int* in_sizes, int n_in,
                              void* d_out, int out_size, void* d_ws, size_t ws_size,
                              hipStream_t stream) {
  const float* x    = (const float*)d_in[0];
  const int*   ei   = (const int*)d_in[1];
  const float* w    = (const float*)d_in[2];
  const float* bias = (const float*)d_in[3];
  float* outx = (float*)d_out;

  // f64-hW tier needs ~174 MB of workspace; f32-hW tier needs ~123 MB.
  if (ws_size >= (size_t)176000000)
    run_all<double>(x, ei, w, bias, outx, (char*)d_ws, stream);
  else
    run_all<float>(x, ei, w, bias, outx, (char*)d_ws, stream);
}

// Round 4
// 1241.263 us; speedup vs baseline: 1.6127x; 1.0595x over previous
//
#include <hip/hip_runtime.h>
#include <stdint.h>

#define NN 100000
#define EE 3200000
#define DD 128
#define KK 50000
#define NB 131072   // rank buckets (2^17)
#define SBLK 512    // NB / 256
#define BB 2048     // band half-width around rank K (band size 2*BB)

using u16 = unsigned short;
using u32 = unsigned int;
using u64 = unsigned long long;

// f32 -> bf16(RNE) -> f32, matching the harness's bf16-quantized reference.
__device__ __forceinline__ float bq(float f) {
  u32 b = __float_as_uint(f);
  b += 0x7FFFu + ((b >> 16) & 1u);
  return __uint_as_float(b & 0xFFFF0000u);
}

// ---------------- degree histogram ----------------
__global__ void k_deg(const int* __restrict__ ei, u32* __restrict__ deg) {
  int e = blockIdx.x * blockDim.x + threadIdx.x;
  if (e < EE) atomicAdd(&deg[ei[EE + e]], 1u);
}

__global__ void k_dinv(const u32* __restrict__ deg, double* __restrict__ dinv) {
  int i = blockIdx.x * blockDim.x + threadIdx.x;
  if (i < NN) dinv[i] = 1.0 / sqrt((double)(deg[i] + 1u)); // +1 self-loop
}

// ---------------- CSR offsets: 3-kernel scan ----------------
#define IBLK 391

__global__ void k_scan1(const u32* __restrict__ deg, u32* __restrict__ bsum) {
  __shared__ u32 sh[256];
  int t = threadIdx.x; int i = blockIdx.x * 256 + t;
  u32 v = (i < NN) ? deg[i] : 0u;
  sh[t] = v; __syncthreads();
  for (int s = 128; s > 0; s >>= 1) { if (t < s) sh[t] += sh[t + s]; __syncthreads(); }
  if (t == 0) bsum[blockIdx.x] = sh[0];
}

__global__ void k_scan2(u32* __restrict__ bsum, int nb) { // 1 block, 512 thr, nb<=512
  __shared__ u32 buf[2][512];
  int t = threadIdx.x;
  u32 v = (t < nb) ? bsum[t] : 0u;
  int a = 0; buf[0][t] = v; __syncthreads();
  for (int s = 1; s < 512; s <<= 1) {
    buf[1 - a][t] = buf[a][t] + ((t >= s) ? buf[a][t - s] : 0u);
    a = 1 - a; __syncthreads();
  }
  if (t < nb) bsum[t] = buf[a][t] - v; // exclusive
}

__global__ void k_scan3(const u32* __restrict__ deg, const u32* __restrict__ bsum,
                        u32* __restrict__ offs, u32* __restrict__ cur) {
  __shared__ u32 buf[2][256];
  int t = threadIdx.x; int i = blockIdx.x * 256 + t;
  u32 v = (i < NN) ? deg[i] : 0u;
  int a = 0; buf[0][t] = v; __syncthreads();
  for (int s = 1; s < 256; s <<= 1) {
    buf[1 - a][t] = buf[a][t] + ((t >= s) ? buf[a][t - s] : 0u);
    a = 1 - a; __syncthreads();
  }
  if (i < NN) {
    u32 exc = buf[a][t] - v + bsum[blockIdx.x];
    offs[i] = exc; cur[i] = exc;
  }
}

__global__ void k_scatter(const int* __restrict__ ei, u32* __restrict__ cur,
                          int* __restrict__ csr) {
  int e = blockIdx.x * blockDim.x + threadIdx.x;
  if (e < EE) {
    int d = ei[EE + e];
    u32 p = atomicAdd(&cur[d], 1u);
    csr[p] = ei[e]; // store src
  }
}

// ------- h = x @ W (f64 accumulate; emit bf16 always, f64 optionally) -------
template <bool W64>
__global__ void k_gemm(const float* __restrict__ x, const float* __restrict__ w,
                       double* __restrict__ hW64, u16* __restrict__ hW16) {
  __shared__ float Wl[DD * DD]; // 64 KiB
  int t = threadIdx.x;
  for (int i = t; i < DD * DD; i += 256) Wl[i] = w[i];
  __syncthreads();
  int base = blockIdx.x * 16;
  int c = t & 127, rh = t >> 7;
  for (int it = 0; it < 8; ++it) {
    int r = base + it * 2 + rh;
    if (r < NN) {
      const float* xr = x + (size_t)r * DD;
      double acc = 0.0;
      #pragma unroll
      for (int k = 0; k < DD; ++k) acc += (double)xr[k] * (double)Wl[k * DD + c];
      if (W64) hW64[(size_t)r * DD + c] = acc;
      u32 b = __float_as_uint((float)acc);
      b += 0x7FFFu + ((b >> 16) & 1u);
      hW16[(size_t)r * DD + c] = (u16)(b >> 16);
    }
  }
}

// ---- gather-aggregate (bf16 rows, f64 accum) + score key + gate, wave/node ----
// lane handles dims (2*lane, 2*lane+1): one u32 = bf16 pair per lane per row.
__global__ void k_agg(const u32* __restrict__ hW16, const double* __restrict__ dinv,
                      const u32* __restrict__ offs, const u32* __restrict__ deg,
                      const int* __restrict__ csr, const float* __restrict__ bias,
                      float* __restrict__ hc, u64* __restrict__ key,
                      double* __restrict__ gate) {
  int node = blockIdx.x * 4 + (threadIdx.x >> 6);
  int lane = threadIdx.x & 63;
  if (node >= NN) return;
  double di = dinv[node];
  double a0 = 0.0, a1 = 0.0;
  u32 o = offs[node], cnt = deg[node];
  for (u32 k = 0; k < cnt; ++k) {
    int s = csr[o + k];
    double nrm = dinv[s] * di;
    u32 wb = hW16[(size_t)s * 64 + lane];
    a0 += (double)__uint_as_float(wb << 16) * nrm;
    a1 += (double)__uint_as_float(wb & 0xFFFF0000u) * nrm;
  }
  double di2 = di * di;
  u32 wb = hW16[(size_t)node * 64 + lane];
  float2 bv = ((const float2*)bias)[lane];
  a0 += (double)__uint_as_float(wb << 16) * di2 + (double)bv.x;
  a1 += (double)__uint_as_float(wb & 0xFFFF0000u) * di2 + (double)bv.y;
  ((float2*)hc)[(size_t)node * 64 + lane] = make_float2((float)a0, (float)a1);
  double ss = a0 * a0 + a1 * a1;
  #pragma unroll
  for (int off = 32; off > 0; off >>= 1) ss += __shfl_xor(ss, off);
  if (lane == 0) {
    double sc = sqrt(ss + 1e-12); // > 0 always
    u64 bits = (u64)__double_as_longlong(sc);
    // strict total order: low 17 bits = (0x1FFFF - node) => lower index wins ties
    key[node] = (bits & ~0x1FFFFull) | (u64)(0x1FFFF - node);
    gate[node] = tanh(sc);
  }
}

// ---------------- exact bucket-rank (approx keys -> full rank) ----------------
__global__ void k_minmax(const u64* __restrict__ key, u64* __restrict__ meta) {
  __shared__ u64 smn[256], smx[256];
  int t = threadIdx.x; int i = blockIdx.x * 256 + t;
  u64 v = (i < NN) ? key[i] : key[0];
  smn[t] = v; smx[t] = v; __syncthreads();
  for (int s = 128; s > 0; s >>= 1) {
    if (t < s) {
      if (smn[t + s] < smn[t]) smn[t] = smn[t + s];
      if (smx[t + s] > smx[t]) smx[t] = smx[t + s];
    }
    __syncthreads();
  }
  if (t == 0) { atomicMin(&meta[0], smn[0]); atomicMax(&meta[1], smx[0]); }
}

__global__ void k_shift(u64* __restrict__ meta) {
  u64 range = meta[1] - meta[0];
  int bits = 64 - __clzll(range | 1ull);
  meta[2] = (u64)(bits > 17 ? bits - 17 : 0);
}

__global__ void k_hist(const u64* __restrict__ key, const u64* __restrict__ meta,
                       u32* __restrict__ barr, u32* __restrict__ bcnt) {
  int i = blockIdx.x * blockDim.x + threadIdx.x;
  if (i >= NN) return;
  u32 b = (u32)((key[i] - meta[0]) >> meta[2]);
  barr[i] = b;
  atomicAdd(&bcnt[b], 1u);
}

__global__ void k_bscan1(const u32* __restrict__ bcnt, u32* __restrict__ bsum2) {
  __shared__ u32 sh[256];
  int t = threadIdx.x; int r = blockIdx.x * 256 + t;
  u32 v = bcnt[NB - 1 - r];
  sh[t] = v; __syncthreads();
  for (int s = 128; s > 0; s >>= 1) { if (t < s) sh[t] += sh[t + s]; __syncthreads(); }
  if (t == 0) bsum2[blockIdx.x] = sh[0];
}

__global__ void k_bscan3(const u32* __restrict__ bcnt, const u32* __restrict__ bsum2,
                         u32* __restrict__ base, u32* __restrict__ bcur) {
  __shared__ u32 buf[2][256];
  int t = threadIdx.x; int r = blockIdx.x * 256 + t;
  int b = NB - 1 - r;
  u32 v = bcnt[b];
  int a = 0; buf[0][t] = v; __syncthreads();
  for (int s = 1; s < 256; s <<= 1) {
    buf[1 - a][t] = buf[a][t] + ((t >= s) ? buf[a][t - s] : 0u);
    a = 1 - a; __syncthreads();
  }
  u32 bs = buf[a][t] - v + bsum2[blockIdx.x]; // suffix-exclusive
  base[b] = bs;
  bcur[b] = NN - bs - v;
}

__global__ void k_bscatter(const u32* __restrict__ barr, u32* __restrict__ bcur,
                           u32* __restrict__ blist) {
  int i = blockIdx.x * blockDim.x + threadIdx.x;
  if (i >= NN) return;
  u32 p = atomicAdd(&bcur[barr[i]], 1u);
  blist[p] = (u32)i;
}

__global__ void k_rank2(const u64* __restrict__ key, const u32* __restrict__ barr,
                        const u32* __restrict__ bcnt, const u32* __restrict__ base,
                        const u32* __restrict__ blist, int* __restrict__ arank) {
  int i = blockIdx.x * blockDim.x + threadIdx.x;
  if (i >= NN) return;
  u32 b = barr[i];
  u64 ki = key[i];
  u32 bs = base[b], cnt = bcnt[b];
  u32 off = NN - bs - cnt;
  u32 gt = 0;
  for (u32 j = 0; j < cnt; ++j) gt += (key[blist[off + j]] > ki) ? 1u : 0u;
  arank[i] = (int)(bs + gt); // full approx rank (a permutation of 0..NN-1)
}

// ---------------- exact band repair ----------------
__global__ void k_bandsel(const int* __restrict__ arank, u32* __restrict__ bandNode) {
  int i = blockIdx.x * blockDim.x + threadIdx.x;
  if (i >= NN) return;
  int r = arank[i] - (KK - BB);
  if (r >= 0 && r < 2 * BB) bandNode[r] = (u32)i;
}

// exact f64 rescore of band nodes from stored f64 hW
__global__ void k_bscore_stored(const u32* __restrict__ bandNode,
                                const double* __restrict__ hW64,
                                const double* __restrict__ dinv,
                                const u32* __restrict__ offs, const u32* __restrict__ deg,
                                const int* __restrict__ csr, const float* __restrict__ bias,
                                u64* __restrict__ ekey) {
  int slot = blockIdx.x * 4 + (threadIdx.x >> 6);
  int lane = threadIdx.x & 63;
  if (slot >= 2 * BB) return;
  int node = (int)bandNode[slot];
  double di = dinv[node];
  double a0 = 0.0, a1 = 0.0;
  u32 o = offs[node], cnt = deg[node];
  for (u32 k = 0; k < cnt; ++k) {
    int s = csr[o + k];
    double nrm = dinv[s] * di;
    double2 hv = ((const double2*)(hW64 + (size_t)s * DD))[lane];
    a0 += hv.x * nrm;
    a1 += hv.y * nrm;
  }
  double di2 = di * di;
  double2 hv = ((const double2*)(hW64 + (size_t)node * DD))[lane];
  float2 bv = ((const float2*)bias)[lane];
  a0 += hv.x * di2 + (double)bv.x;
  a1 += hv.y * di2 + (double)bv.y;
  double ss = a0 * a0 + a1 * a1;
  #pragma unroll
  for (int off = 32; off > 0; off >>= 1) ss += __shfl_xor(ss, off);
  if (lane == 0) {
    double sc = sqrt(ss + 1e-12);
    u64 bits = (u64)__double_as_longlong(sc);
    ekey[slot] = (bits & ~0x1FFFFull) | (u64)(0x1FFFF - node);
  }
}

// exact f64 rescore recomputing h rows on the fly (low-ws fallback)
__global__ void k_bscore_onfly(const u32* __restrict__ bandNode,
                               const float* __restrict__ x, const float* __restrict__ w,
                               const double* __restrict__ dinv,
                               const u32* __restrict__ offs, const u32* __restrict__ deg,
                               const int* __restrict__ csr, const float* __restrict__ bias,
                               u64* __restrict__ ekey) {
  int slot = blockIdx.x * 4 + (threadIdx.x >> 6);
  int lane = threadIdx.x & 63;
  if (slot >= 2 * BB) return;
  int node = (int)bandNode[slot];
  double di = dinv[node];
  double a0 = 0.0, a1 = 0.0;
  u32 o = offs[node], cnt = deg[node];
  for (u32 k = 0; k <= cnt; ++k) { // last iter = self row
    int s = (k < cnt) ? csr[o + k] : node;
    double wgt = (k < cnt) ? (dinv[s] * di) : (di * di);
    const float* xs = x + (size_t)s * DD;
    double h0 = 0.0, h1 = 0.0;
    for (int kk = 0; kk < DD; ++kk) {
      double xv = (double)xs[kk];
      h0 += xv * (double)w[kk * DD + 2 * lane];
      h1 += xv * (double)w[kk * DD + 2 * lane + 1];
    }
    a0 += h0 * wgt;
    a1 += h1 * wgt;
  }
  float2 bv = ((const float2*)bias)[lane];
  a0 += (double)bv.x;
  a1 += (double)bv.y;
  double ss = a0 * a0 + a1 * a1;
  #pragma unroll
  for (int off = 32; off > 0; off >>= 1) ss += __shfl_xor(ss, off);
  if (lane == 0) {
    double sc = sqrt(ss + 1e-12);
    u64 bits = (u64)__double_as_longlong(sc);
    ekey[slot] = (bits & ~0x1FFFFull) | (u64)(0x1FFFF - node);
  }
}

__global__ void k_bandrank(const u64* __restrict__ ekey, u32* __restrict__ brank) {
  __shared__ u64 sk[2 * BB]; // 32 KiB
  int t = threadIdx.x;
  for (int j = t; j < 2 * BB; j += 256) sk[j] = ekey[j];
  __syncthreads();
  int idx = blockIdx.x * 256 + t;
  u64 kk = sk[idx];
  u32 c = 0;
  for (int j = 0; j < 2 * BB; ++j) c += (sk[j] > kk) ? 1u : 0u;
  brank[idx] = c;
}

__global__ void k_pos2(const int* __restrict__ arank, const u32* __restrict__ brank,
                       int* __restrict__ pos) {
  int i = blockIdx.x * blockDim.x + threadIdx.x;
  if (i >= NN) return;
  int r = arank[i];
  int p;
  if (r < KK - BB) p = r;                       // surely kept
  else if (r < KK + BB) {                       // band: exact order decides
    u32 br = brank[r - (KK - BB)];
    p = (br < BB) ? (KK - BB + (int)br) : -1;
  } else p = -1;                                // surely dropped
  pos[i] = p;
}

// ---------------- outputs (f32, bf16-RNE-quantized) ----------------
__global__ void k_xout(const float* __restrict__ hc, const double* __restrict__ gate,
                       const int* __restrict__ pos, float* __restrict__ outx) {
  int id = blockIdx.x * blockDim.x + threadIdx.x;
  if (id >= NN * DD) return;
  int i = id >> 7, d = id & 127;
  int p = pos[i];
  if (p < 0) return;
  float v = (float)((double)hc[(size_t)i * DD + d] * gate[i]);
  outx[(size_t)p * DD + d] = bq(v);
}

__global__ void k_edges(const int* __restrict__ ei, const int* __restrict__ pos,
                        float* __restrict__ osrc, float* __restrict__ odst,
                        float* __restrict__ omask) {
  int e = blockIdx.x * blockDim.x + threadIdx.x;
  if (e >= EE) return;
  int ns = pos[ei[e]];
  int nd = pos[ei[EE + e]];
  bool m = (ns >= 0) && (nd >= 0);
  osrc[e] = m ? bq((float)ns) : -1.0f;
  odst[e] = m ? bq((float)nd) : -1.0f;
  omask[e] = m ? 1.0f : 0.0f;
}

// ---------------- driver ----------------
template <bool STORED64>
static void run_all(const float* x, const int* ei, const float* w, const float* bias,
                    float* outx, char* ws, hipStream_t stream) {
  size_t off = 0;
  auto alloc = [&](size_t b) -> void* {
    void* p = ws + off; off += (b + 255) & ~(size_t)255; return p;
  };
  double* hW64  = STORED64 ? (double*)alloc((size_t)NN * DD * 8) : nullptr;
  u16*    hW16  = (u16*)alloc((size_t)NN * DD * 2);
  float*  hc    = (float*)alloc((size_t)NN * DD * 4);
  double* dinv  = (double*)alloc((size_t)NN * 8);
  double* gate  = (double*)alloc((size_t)NN * 8);
  u64*    key   = (u64*)alloc((size_t)NN * 8);
  u32*    deg   = (u32*)alloc((size_t)NN * 4);
  u32*    offs  = (u32*)alloc((size_t)NN * 4);
  u32*    cur   = (u32*)alloc((size_t)NN * 4);
  int*    csr   = (int*)alloc((size_t)EE * 4);
  int*    arank = (int*)alloc((size_t)NN * 4);
  int*    pos   = (int*)alloc((size_t)NN * 4);
  u32*    bsum  = (u32*)alloc(512 * 4);
  u64*    meta  = (u64*)alloc(4 * 8);
  u32*    bcnt  = (u32*)alloc((size_t)NB * 4);
  u32*    base  = (u32*)alloc((size_t)NB * 4);
  u32*    bcur  = (u32*)alloc((size_t)NB * 4);
  u32*    bsum2 = (u32*)alloc(SBLK * 4);
  u32*    barr  = (u32*)alloc((size_t)NN * 4);
  u32*    blist = (u32*)alloc((size_t)NN * 4);
  u32*    bandNode = (u32*)alloc((size_t)2 * BB * 4);
  u64*    ekey     = (u64*)alloc((size_t)2 * BB * 8);
  u32*    brank    = (u32*)alloc((size_t)2 * BB * 4);

  hipMemsetAsync(deg, 0, (size_t)NN * 4, stream);
  hipMemsetAsync(bcnt, 0, (size_t)NB * 4, stream);
  hipMemsetAsync(meta, 0xFF, 8, stream);      // kmin = ~0
  hipMemsetAsync(meta + 1, 0x00, 8, stream);  // kmax = 0

  k_deg<<<(EE + 255) / 256, 256, 0, stream>>>(ei, deg);
  k_dinv<<<(NN + 255) / 256, 256, 0, stream>>>(deg, dinv);
  k_scan1<<<IBLK, 256, 0, stream>>>(deg, bsum);
  k_scan2<<<1, 512, 0, stream>>>(bsum, IBLK);
  k_scan3<<<IBLK, 256, 0, stream>>>(deg, bsum, offs, cur);
  k_scatter<<<(EE + 255) / 256, 256, 0, stream>>>(ei, cur, csr);
  k_gemm<STORED64><<<(NN + 15) / 16, 256, 0, stream>>>(x, w, hW64, hW16);
  k_agg<<<(NN + 3) / 4, 256, 0, stream>>>((const u32*)hW16, dinv, offs, deg, csr, bias,
                                          hc, key, gate);
  k_minmax<<<IBLK, 256, 0, stream>>>(key, meta);
  k_shift<<<1, 1, 0, stream>>>(meta);
  k_hist<<<(NN + 255) / 256, 256, 0, stream>>>(key, meta, barr, bcnt);
  k_bscan1<<<SBLK, 256, 0, stream>>>(bcnt, bsum2);
  k_scan2<<<1, 512, 0, stream>>>(bsum2, SBLK);
  k_bscan3<<<SBLK, 256, 0, stream>>>(bcnt, bsum2, base, bcur);
  k_bscatter<<<(NN + 255) / 256, 256, 0, stream>>>(barr, bcur, blist);
  k_rank2<<<(NN + 255) / 256, 256, 0, stream>>>(key, barr, bcnt, base, blist, arank);
  // exact band repair (membership == full-f64 ordering)
  k_bandsel<<<(NN + 255) / 256, 256, 0, stream>>>(arank, bandNode);
  if (STORED64)
    k_bscore_stored<<<(2 * BB) / 4, 256, 0, stream>>>(bandNode, hW64, dinv, offs, deg,
                                                      csr, bias, ekey);
  else
    k_bscore_onfly<<<(2 * BB) / 4, 256, 0, stream>>>(bandNode, x, w, dinv, offs, deg,
                                                     csr, bias, ekey);
  k_bandrank<<<(2 * BB) / 256, 256, 0, stream>>>(ekey, brank);
  k_pos2<<<(NN + 255) / 256, 256, 0, stream>>>(arank, brank, pos);
  k_xout<<<(NN * DD + 255) / 256, 256, 0, stream>>>(hc, gate, pos, outx);
  float* oei = outx + (size_t)KK * DD;
  k_edges<<<(EE + 255) / 256, 256, 0, stream>>>(ei, pos, oei, oei + EE, oei + 2 * (size_t)EE);
}

extern "C" void kernel_launch(void* const* d_in, const int* in_sizes, int n_in,
                              void* d_out, int out_size, void* d_ws, size_t ws_size,
                              hipStream_t stream) {
  const float* x    = (const float*)d_in[0];
  const int*   ei   = (const int*)d_in[1];
  const float* w    = (const float*)d_in[2];
  const float* bias = (const float*)d_in[3];
  float* outx = (float*)d_out;

  // stored-f64 repair tier needs ~199 MB; on-the-fly repair tier needs ~97 MB.
  if (ws_size >= (size_t)202000000)
    run_all<true>(x, ei, w, bias, outx, (char*)d_ws, stream);
  else
    run_all<false>(x, ei, w, bias, outx, (char*)d_ws, stream);
}

// Round 5
// 1020.399 us; speedup vs baseline: 1.9618x; 1.2164x over previous
//
#include <hip/hip_runtime.h>
#include <hip/hip_fp16.h>
#include <stdint.h>

#define NN 100000
#define EE 3200000
#define DD 128
#define KK 50000
#define NB 131072   // rank buckets (2^17)
#define SBLK 512    // NB / 256
#define BB 2048     // band half-width around rank K (band size 2*BB)

using u16 = unsigned short;
using u32 = unsigned int;
using u64 = unsigned long long;

// f32 -> bf16(RNE) -> f32, matching the harness's bf16-quantized reference.
__device__ __forceinline__ float bq(float f) {
  u32 b = __float_as_uint(f);
  b += 0x7FFFu + ((b >> 16) & 1u);
  return __uint_as_float(b & 0xFFFF0000u);
}

// ---------------- degree histogram ----------------
__global__ void k_deg(const int* __restrict__ ei, u32* __restrict__ deg) {
  int e = blockIdx.x * blockDim.x + threadIdx.x;
  if (e < EE) atomicAdd(&deg[ei[EE + e]], 1u);
}

__global__ void k_dinv(const u32* __restrict__ deg, double* __restrict__ dinv64,
                       float* __restrict__ dinv32) {
  int i = blockIdx.x * blockDim.x + threadIdx.x;
  if (i < NN) {
    double d = 1.0 / sqrt((double)(deg[i] + 1u)); // +1 self-loop
    dinv64[i] = d;
    dinv32[i] = (float)d;
  }
}

// ---------------- CSR offsets: 3-kernel scan ----------------
#define IBLK 391

__global__ void k_scan1(const u32* __restrict__ deg, u32* __restrict__ bsum) {
  __shared__ u32 sh[256];
  int t = threadIdx.x; int i = blockIdx.x * 256 + t;
  u32 v = (i < NN) ? deg[i] : 0u;
  sh[t] = v; __syncthreads();
  for (int s = 128; s > 0; s >>= 1) { if (t < s) sh[t] += sh[t + s]; __syncthreads(); }
  if (t == 0) bsum[blockIdx.x] = sh[0];
}

__global__ void k_scan2(u32* __restrict__ bsum, int nb) { // 1 block, 512 thr, nb<=512
  __shared__ u32 buf[2][512];
  int t = threadIdx.x;
  u32 v = (t < nb) ? bsum[t] : 0u;
  int a = 0; buf[0][t] = v; __syncthreads();
  for (int s = 1; s < 512; s <<= 1) {
    buf[1 - a][t] = buf[a][t] + ((t >= s) ? buf[a][t - s] : 0u);
    a = 1 - a; __syncthreads();
  }
  if (t < nb) bsum[t] = buf[a][t] - v; // exclusive
}

__global__ void k_scan3(const u32* __restrict__ deg, const u32* __restrict__ bsum,
                        u32* __restrict__ offs, u32* __restrict__ cur) {
  __shared__ u32 buf[2][256];
  int t = threadIdx.x; int i = blockIdx.x * 256 + t;
  u32 v = (i < NN) ? deg[i] : 0u;
  int a = 0; buf[0][t] = v; __syncthreads();
  for (int s = 1; s < 256; s <<= 1) {
    buf[1 - a][t] = buf[a][t] + ((t >= s) ? buf[a][t - s] : 0u);
    a = 1 - a; __syncthreads();
  }
  if (i < NN) {
    u32 exc = buf[a][t] - v + bsum[blockIdx.x];
    offs[i] = exc; cur[i] = exc;
  }
}

__global__ void k_scatter(const int* __restrict__ ei, u32* __restrict__ cur,
                          int* __restrict__ csr) {
  int e = blockIdx.x * blockDim.x + threadIdx.x;
  if (e < EE) {
    int d = ei[EE + e];
    u32 p = atomicAdd(&cur[d], 1u);
    csr[p] = ei[e]; // store src
  }
}

// ------- h = x @ W (f32 accumulate; emit fp16) -------
__global__ void k_gemm(const float* __restrict__ x, const float* __restrict__ w,
                       u16* __restrict__ hW16) {
  __shared__ float Wl[DD * DD]; // 64 KiB
  int t = threadIdx.x;
  for (int i = t; i < DD * DD; i += 256) Wl[i] = w[i];
  __syncthreads();
  int base = blockIdx.x * 16;
  int c = t & 127, rh = t >> 7;
  for (int it = 0; it < 8; ++it) {
    int r = base + it * 2 + rh;
    if (r < NN) {
      const float4* xr = (const float4*)(x + (size_t)r * DD);
      float acc = 0.0f;
      #pragma unroll 4
      for (int k4 = 0; k4 < 32; ++k4) {
        float4 xv = xr[k4];
        int kb = k4 * 4;
        acc += xv.x * Wl[kb * DD + c];
        acc += xv.y * Wl[(kb + 1) * DD + c];
        acc += xv.z * Wl[(kb + 2) * DD + c];
        acc += xv.w * Wl[(kb + 3) * DD + c];
      }
      hW16[(size_t)r * DD + c] = __half_as_ushort(__float2half(acc));
    }
  }
}

// ---- gather-aggregate (fp16 rows, f32 accum, unroll-4) + key + gate ----
// lane handles dims (2*lane, 2*lane+1): one u32 = half2 per lane per row.
__global__ void k_agg(const u32* __restrict__ hw, const float* __restrict__ dinv32,
                      const u32* __restrict__ offs, const u32* __restrict__ deg,
                      const int* __restrict__ csr, const float* __restrict__ bias,
                      float* __restrict__ hc, u64* __restrict__ key,
                      float* __restrict__ gate) {
  int node = blockIdx.x * 4 + (threadIdx.x >> 6);
  int lane = threadIdx.x & 63;
  if (node >= NN) return;
  float di = dinv32[node];
  float a0 = 0.0f, a1 = 0.0f;
  u32 o = offs[node], cnt = deg[node];
  u32 k = 0;
  for (; k + 4 <= cnt; k += 4) {
    int s0 = csr[o + k], s1 = csr[o + k + 1], s2 = csr[o + k + 2], s3 = csr[o + k + 3];
    float n0 = dinv32[s0] * di, n1 = dinv32[s1] * di;
    float n2 = dinv32[s2] * di, n3 = dinv32[s3] * di;
    u32 w0 = hw[(size_t)s0 * 64 + lane];
    u32 w1 = hw[(size_t)s1 * 64 + lane];
    u32 w2 = hw[(size_t)s2 * 64 + lane];
    u32 w3 = hw[(size_t)s3 * 64 + lane];
    float2 h0 = __half22float2(*(__half2*)&w0);
    float2 h1 = __half22float2(*(__half2*)&w1);
    float2 h2 = __half22float2(*(__half2*)&w2);
    float2 h3 = __half22float2(*(__half2*)&w3);
    a0 += h0.x * n0 + h1.x * n1 + h2.x * n2 + h3.x * n3;
    a1 += h0.y * n0 + h1.y * n1 + h2.y * n2 + h3.y * n3;
  }
  for (; k < cnt; ++k) {
    int s = csr[o + k];
    float nrm = dinv32[s] * di;
    u32 wb = hw[(size_t)s * 64 + lane];
    float2 hv = __half22float2(*(__half2*)&wb);
    a0 += hv.x * nrm;
    a1 += hv.y * nrm;
  }
  float di2 = di * di;
  u32 wb = hw[(size_t)node * 64 + lane];
  float2 hv = __half22float2(*(__half2*)&wb);
  float2 bv = ((const float2*)bias)[lane];
  a0 += hv.x * di2 + bv.x;
  a1 += hv.y * di2 + bv.y;
  ((float2*)hc)[(size_t)node * 64 + lane] = make_float2(a0, a1);
  float ss = a0 * a0 + a1 * a1;
  #pragma unroll
  for (int off = 32; off > 0; off >>= 1) ss += __shfl_xor(ss, off);
  if (lane == 0) {
    // approx key: f32 ss bits (monotone in score, ss >= 0);
    // low 17 bits = (0x1FFFF - node) => lower index wins ties
    u32 sb = __float_as_uint(ss);
    key[node] = ((u64)sb << 17) | (u64)(0x1FFFF - node);
    gate[node] = tanhf(sqrtf(ss + 1e-12f));
  }
}

// ---------------- exact bucket-rank (approx keys -> full rank) ----------------
__global__ void k_minmax(const u64* __restrict__ key, u64* __restrict__ meta) {
  __shared__ u64 smn[256], smx[256];
  int t = threadIdx.x; int i = blockIdx.x * 256 + t;
  u64 v = (i < NN) ? key[i] : key[0];
  smn[t] = v; smx[t] = v; __syncthreads();
  for (int s = 128; s > 0; s >>= 1) {
    if (t < s) {
      if (smn[t + s] < smn[t]) smn[t] = smn[t + s];
      if (smx[t + s] > smx[t]) smx[t] = smx[t + s];
    }
    __syncthreads();
  }
  if (t == 0) { atomicMin(&meta[0], smn[0]); atomicMax(&meta[1], smx[0]); }
}

__global__ void k_shift(u64* __restrict__ meta) {
  u64 range = meta[1] - meta[0];
  int bits = 64 - __clzll(range | 1ull);
  meta[2] = (u64)(bits > 17 ? bits - 17 : 0);
}

__global__ void k_hist(const u64* __restrict__ key, const u64* __restrict__ meta,
                       u32* __restrict__ barr, u32* __restrict__ bcnt) {
  int i = blockIdx.x * blockDim.x + threadIdx.x;
  if (i >= NN) return;
  u32 b = (u32)((key[i] - meta[0]) >> meta[2]);
  barr[i] = b;
  atomicAdd(&bcnt[b], 1u);
}

__global__ void k_bscan1(const u32* __restrict__ bcnt, u32* __restrict__ bsum2) {
  __shared__ u32 sh[256];
  int t = threadIdx.x; int r = blockIdx.x * 256 + t;
  u32 v = bcnt[NB - 1 - r];
  sh[t] = v; __syncthreads();
  for (int s = 128; s > 0; s >>= 1) { if (t < s) sh[t] += sh[t + s]; __syncthreads(); }
  if (t == 0) bsum2[blockIdx.x] = sh[0];
}

__global__ void k_bscan3(const u32* __restrict__ bcnt, const u32* __restrict__ bsum2,
                         u32* __restrict__ base, u32* __restrict__ bcur) {
  __shared__ u32 buf[2][256];
  int t = threadIdx.x; int r = blockIdx.x * 256 + t;
  int b = NB - 1 - r;
  u32 v = bcnt[b];
  int a = 0; buf[0][t] = v; __syncthreads();
  for (int s = 1; s < 256; s <<= 1) {
    buf[1 - a][t] = buf[a][t] + ((t >= s) ? buf[a][t - s] : 0u);
    a = 1 - a; __syncthreads();
  }
  u32 bs = buf[a][t] - v + bsum2[blockIdx.x]; // suffix-exclusive
  base[b] = bs;
  bcur[b] = NN - bs - v;
}

__global__ void k_bscatter(const u32* __restrict__ barr, u32* __restrict__ bcur,
                           u32* __restrict__ blist) {
  int i = blockIdx.x * blockDim.x + threadIdx.x;
  if (i >= NN) return;
  u32 p = atomicAdd(&bcur[barr[i]], 1u);
  blist[p] = (u32)i;
}

__global__ void k_rank2(const u64* __restrict__ key, const u32* __restrict__ barr,
                        const u32* __restrict__ bcnt, const u32* __restrict__ base,
                        const u32* __restrict__ blist, int* __restrict__ arank) {
  int i = blockIdx.x * blockDim.x + threadIdx.x;
  if (i >= NN) return;
  u32 b = barr[i];
  u64 ki = key[i];
  u32 bs = base[b], cnt = bcnt[b];
  u32 off = NN - bs - cnt;
  u32 gt = 0;
  for (u32 j = 0; j < cnt; ++j) gt += (key[blist[off + j]] > ki) ? 1u : 0u;
  arank[i] = (int)(bs + gt); // full approx rank (a permutation of 0..NN-1)
}

// ---------------- exact band repair ----------------
__global__ void k_bandsel(const int* __restrict__ arank, u32* __restrict__ bandNode) {
  int i = blockIdx.x * blockDim.x + threadIdx.x;
  if (i >= NN) return;
  int r = arank[i] - (KK - BB);
  if (r >= 0 && r < 2 * BB) bandNode[r] = (u32)i;
}

// exact f64 rescore via linearity: a = (sum_s wgt_s * x_s) @ W + bias
__global__ void k_bscore(const u32* __restrict__ bandNode,
                         const float* __restrict__ x, const float* __restrict__ w,
                         const double* __restrict__ dinv64,
                         const u32* __restrict__ offs, const u32* __restrict__ deg,
                         const int* __restrict__ csr, const float* __restrict__ bias,
                         u64* __restrict__ ekey) {
  __shared__ double zsh[4][DD]; // 4 KiB
  int wid = threadIdx.x >> 6;
  int lane = threadIdx.x & 63;
  int slot = blockIdx.x * 4 + wid;
  int node = (int)bandNode[slot];
  double di = dinv64[node];
  double z0 = 0.0, z1 = 0.0;
  u32 o = offs[node], cnt = deg[node];
  for (u32 k = 0; k <= cnt; ++k) { // last iter = self row
    int s = (k < cnt) ? csr[o + k] : node;
    double wgt = (k < cnt) ? (dinv64[s] * di) : (di * di);
    float2 xv = ((const float2*)x)[(size_t)s * 64 + lane];
    z0 += (double)xv.x * wgt;
    z1 += (double)xv.y * wgt;
  }
  zsh[wid][2 * lane] = z0;
  zsh[wid][2 * lane + 1] = z1;
  __syncthreads();
  float2 bv = ((const float2*)bias)[lane];
  double a0 = (double)bv.x, a1 = (double)bv.y;
  for (int kk = 0; kk < DD; ++kk) {
    double zk = zsh[wid][kk];
    float2 wv = ((const float2*)w)[kk * 64 + lane];
    a0 += zk * (double)wv.x;
    a1 += zk * (double)wv.y;
  }
  double ss = a0 * a0 + a1 * a1;
  #pragma unroll
  for (int off = 32; off > 0; off >>= 1) ss += __shfl_xor(ss, off);
  if (lane == 0) {
    double sc = sqrt(ss + 1e-12);
    u64 bits = (u64)__double_as_longlong(sc);
    ekey[slot] = (bits & ~0x1FFFFull) | (u64)(0x1FFFF - node);
  }
}

__global__ void k_bandrank(const u64* __restrict__ ekey, u32* __restrict__ brank) {
  __shared__ u64 sk[2 * BB]; // 32 KiB
  int t = threadIdx.x;
  for (int j = t; j < 2 * BB; j += 256) sk[j] = ekey[j];
  __syncthreads();
  int idx = blockIdx.x * 256 + t;
  u64 kk = sk[idx];
  u32 c = 0;
  for (int j = 0; j < 2 * BB; ++j) c += (sk[j] > kk) ? 1u : 0u;
  brank[idx] = c;
}

__global__ void k_pos2(const int* __restrict__ arank, const u32* __restrict__ brank,
                       int* __restrict__ pos) {
  int i = blockIdx.x * blockDim.x + threadIdx.x;
  if (i >= NN) return;
  int r = arank[i];
  int p;
  if (r < KK - BB) p = r;                       // surely kept
  else if (r < KK + BB) {                       // band: exact order decides
    u32 br = brank[r - (KK - BB)];
    p = (br < BB) ? (KK - BB + (int)br) : -1;
  } else p = -1;                                // surely dropped
  pos[i] = p;
}

// ---------------- outputs (f32, bf16-RNE-quantized) ----------------
__global__ void k_xout(const float* __restrict__ hc, const float* __restrict__ gate,
                       const int* __restrict__ pos, float* __restrict__ outx) {
  int id = blockIdx.x * blockDim.x + threadIdx.x;
  if (id >= NN * DD) return;
  int i = id >> 7, d = id & 127;
  int p = pos[i];
  if (p < 0) return;
  float v = hc[(size_t)i * DD + d] * gate[i];
  outx[(size_t)p * DD + d] = bq(v);
}

__global__ void k_edges(const int* __restrict__ ei, const int* __restrict__ pos,
                        float* __restrict__ osrc, float* __restrict__ odst,
                        float* __restrict__ omask) {
  int e = blockIdx.x * blockDim.x + threadIdx.x;
  if (e >= EE) return;
  int ns = pos[ei[e]];
  int nd = pos[ei[EE + e]];
  bool m = (ns >= 0) && (nd >= 0);
  osrc[e] = m ? bq((float)ns) : -1.0f;
  odst[e] = m ? bq((float)nd) : -1.0f;
  omask[e] = m ? 1.0f : 0.0f;
}

// ---------------- driver ----------------
extern "C" void kernel_launch(void* const* d_in, const int* in_sizes, int n_in,
                              void* d_out, int out_size, void* d_ws, size_t ws_size,
                              hipStream_t stream) {
  const float* x    = (const float*)d_in[0];
  const int*   ei   = (const int*)d_in[1];
  const float* w    = (const float*)d_in[2];
  const float* bias = (const float*)d_in[3];
  float* outx = (float*)d_out;
  char* ws = (char*)d_ws;

  size_t off = 0;
  auto alloc = [&](size_t b) -> void* {
    void* p = ws + off; off += (b + 255) & ~(size_t)255; return p;
  };
  u16*    hW16   = (u16*)alloc((size_t)NN * DD * 2);
  float*  hc     = (float*)alloc((size_t)NN * DD * 4);
  double* dinv64 = (double*)alloc((size_t)NN * 8);
  float*  dinv32 = (float*)alloc((size_t)NN * 4);
  float*  gate   = (float*)alloc((size_t)NN * 4);
  u64*    key    = (u64*)alloc((size_t)NN * 8);
  u32*    deg    = (u32*)alloc((size_t)NN * 4);
  u32*    offs   = (u32*)alloc((size_t)NN * 4);
  u32*    cur    = (u32*)alloc((size_t)NN * 4);
  int*    csr    = (int*)alloc((size_t)EE * 4);
  int*    arank  = (int*)alloc((size_t)NN * 4);
  int*    pos    = (int*)alloc((size_t)NN * 4);
  u32*    bsum   = (u32*)alloc(512 * 4);
  u64*    meta   = (u64*)alloc(4 * 8);
  u32*    bcnt   = (u32*)alloc((size_t)NB * 4);
  u32*    base   = (u32*)alloc((size_t)NB * 4);
  u32*    bcur   = (u32*)alloc((size_t)NB * 4);
  u32*    bsum2  = (u32*)alloc(SBLK * 4);
  u32*    barr   = (u32*)alloc((size_t)NN * 4);
  u32*    blist  = (u32*)alloc((size_t)NN * 4);
  u32*    bandNode = (u32*)alloc((size_t)2 * BB * 4);
  u64*    ekey     = (u64*)alloc((size_t)2 * BB * 8);
  u32*    brank    = (u32*)alloc((size_t)2 * BB * 4);

  hipMemsetAsync(deg, 0, (size_t)NN * 4, stream);
  hipMemsetAsync(bcnt, 0, (size_t)NB * 4, stream);
  hipMemsetAsync(meta, 0xFF, 8, stream);      // kmin = ~0
  hipMemsetAsync(meta + 1, 0x00, 8, stream);  // kmax = 0

  k_deg<<<(EE + 255) / 256, 256, 0, stream>>>(ei, deg);
  k_dinv<<<(NN + 255) / 256, 256, 0, stream>>>(deg, dinv64, dinv32);
  k_scan1<<<IBLK, 256, 0, stream>>>(deg, bsum);
  k_scan2<<<1, 512, 0, stream>>>(bsum, IBLK);
  k_scan3<<<IBLK, 256, 0, stream>>>(deg, bsum, offs, cur);
  k_scatter<<<(EE + 255) / 256, 256, 0, stream>>>(ei, cur, csr);
  k_gemm<<<(NN + 15) / 16, 256, 0, stream>>>(x, w, hW16);
  k_agg<<<(NN + 3) / 4, 256, 0, stream>>>((const u32*)hW16, dinv32, offs, deg, csr,
                                          bias, hc, key, gate);
  k_minmax<<<IBLK, 256, 0, stream>>>(key, meta);
  k_shift<<<1, 1, 0, stream>>>(meta);
  k_hist<<<(NN + 255) / 256, 256, 0, stream>>>(key, meta, barr, bcnt);
  k_bscan1<<<SBLK, 256, 0, stream>>>(bcnt, bsum2);
  k_scan2<<<1, 512, 0, stream>>>(bsum2, SBLK);
  k_bscan3<<<SBLK, 256, 0, stream>>>(bcnt, bsum2, base, bcur);
  k_bscatter<<<(NN + 255) / 256, 256, 0, stream>>>(barr, bcur, blist);
  k_rank2<<<(NN + 255) / 256, 256, 0, stream>>>(key, barr, bcnt, base, blist, arank);
  // exact band repair (f64 truth via linearity)
  k_bandsel<<<(NN + 255) / 256, 256, 0, stream>>>(arank, bandNode);
  k_bscore<<<(2 * BB) / 4, 256, 0, stream>>>(bandNode, x, w, dinv64, offs, deg, csr,
                                             bias, ekey);
  k_bandrank<<<(2 * BB) / 256, 256, 0, stream>>>(ekey, brank);
  k_pos2<<<(NN + 255) / 256, 256, 0, stream>>>(arank, brank, pos);
  k_xout<<<(NN * DD + 255) / 256, 256, 0, stream>>>(hc, gate, pos, outx);
  float* oei = outx + (size_t)KK * DD;
  k_edges<<<(EE + 255) / 256, 256, 0, stream>>>(ei, pos, oei, oei + EE, oei + 2 * (size_t)EE);
}

// Round 6
// 778.649 us; speedup vs baseline: 2.5709x; 1.3105x over previous
//
#include <hip/hip_runtime.h>
#include <hip/hip_fp16.h>
#include <stdint.h>

#define NN 100000
#define EE 3200000
#define DD 128
#define KK 50000
#define NB 131072   // rank buckets (2^17)
#define SBLK 512    // NB / 256
#define BB 2048     // band half-width around rank K (band size 2*BB)

using u16 = unsigned short;
using u32 = unsigned int;
using u64 = unsigned long long;

typedef _Float16 f16x8 __attribute__((ext_vector_type(8)));
typedef float f32x4 __attribute__((ext_vector_type(4)));

// f32 -> bf16(RNE) -> f32, matching the harness's bf16-quantized reference.
__device__ __forceinline__ float bq(float f) {
  u32 b = __float_as_uint(f);
  b += 0x7FFFu + ((b >> 16) & 1u);
  return __uint_as_float(b & 0xFFFF0000u);
}

// ---------------- degree histogram ----------------
__global__ void k_deg(const int* __restrict__ ei, u32* __restrict__ deg) {
  int e = blockIdx.x * blockDim.x + threadIdx.x;
  if (e < EE) atomicAdd(&deg[ei[EE + e]], 1u);
}

__global__ void k_dinv(const u32* __restrict__ deg, double* __restrict__ dinv64,
                       float* __restrict__ dinv32) {
  int i = blockIdx.x * blockDim.x + threadIdx.x;
  if (i < NN) {
    double d = 1.0 / sqrt((double)(deg[i] + 1u)); // +1 self-loop
    dinv64[i] = d;
    dinv32[i] = (float)d;
  }
}

// ---------------- CSR offsets: 3-kernel scan ----------------
#define IBLK 391

__global__ void k_scan1(const u32* __restrict__ deg, u32* __restrict__ bsum) {
  __shared__ u32 sh[256];
  int t = threadIdx.x; int i = blockIdx.x * 256 + t;
  u32 v = (i < NN) ? deg[i] : 0u;
  sh[t] = v; __syncthreads();
  for (int s = 128; s > 0; s >>= 1) { if (t < s) sh[t] += sh[t + s]; __syncthreads(); }
  if (t == 0) bsum[blockIdx.x] = sh[0];
}

__global__ void k_scan2(u32* __restrict__ bsum, int nb) { // 1 block, 512 thr, nb<=512
  __shared__ u32 buf[2][512];
  int t = threadIdx.x;
  u32 v = (t < nb) ? bsum[t] : 0u;
  int a = 0; buf[0][t] = v; __syncthreads();
  for (int s = 1; s < 512; s <<= 1) {
    buf[1 - a][t] = buf[a][t] + ((t >= s) ? buf[a][t - s] : 0u);
    a = 1 - a; __syncthreads();
  }
  if (t < nb) bsum[t] = buf[a][t] - v; // exclusive
}

__global__ void k_scan3(const u32* __restrict__ deg, const u32* __restrict__ bsum,
                        u32* __restrict__ offs, u32* __restrict__ cur) {
  __shared__ u32 buf[2][256];
  int t = threadIdx.x; int i = blockIdx.x * 256 + t;
  u32 v = (i < NN) ? deg[i] : 0u;
  int a = 0; buf[0][t] = v; __syncthreads();
  for (int s = 1; s < 256; s <<= 1) {
    buf[1 - a][t] = buf[a][t] + ((t >= s) ? buf[a][t - s] : 0u);
    a = 1 - a; __syncthreads();
  }
  if (i < NN) {
    u32 exc = buf[a][t] - v + bsum[blockIdx.x];
    offs[i] = exc; cur[i] = exc;
  }
}

__global__ void k_scatter(const int* __restrict__ ei, u32* __restrict__ cur,
                          int* __restrict__ csr) {
  int e = blockIdx.x * blockDim.x + threadIdx.x;
  if (e < EE) {
    int d = ei[EE + e];
    u32 p = atomicAdd(&cur[d], 1u);
    csr[p] = ei[e]; // store src
  }
}

// ------- W -> per-lane f16 MFMA fragments -------
// wfrag[(kstep*8 + ctt)*64 + lane] = B[k][c], k=(lane>>4)*8+j+kstep*32, c=ctt*16+(lane&15)
__global__ void k_wfrag(const float* __restrict__ w, f16x8* __restrict__ wfrag) {
  int idx = blockIdx.x * 256 + threadIdx.x; // 2048 total
  int lane = idx & 63;
  int ctt = (idx >> 6) & 7;
  int kstep = idx >> 9;
  int c = ctt * 16 + (lane & 15);
  int kbase = (lane >> 4) * 8 + kstep * 32;
  f16x8 v;
  #pragma unroll
  for (int j = 0; j < 8; ++j) v[j] = (_Float16)w[(kbase + j) * DD + c];
  wfrag[idx] = v;
}

// ------- h = x @ W via MFMA 16x16x32 f16 (f32 accumulate, emit fp16) -------
__global__ void __launch_bounds__(256) k_gemm_mfma(const float* __restrict__ x,
                                                   const f16x8* __restrict__ wfrag,
                                                   u16* __restrict__ hW16) {
  int wid = threadIdx.x >> 6, lane = threadIdx.x & 63;
  int rowbase = blockIdx.x * 32 + (wid & 1) * 16;
  int colgrp = wid >> 1; // 0..1, 64 cols each
  int row = rowbase + (lane & 15);
  int klane = (lane >> 4) * 8;

  f32x4 acc[4] = {{0,0,0,0},{0,0,0,0},{0,0,0,0},{0,0,0,0}};
  const float* xr = x + (size_t)row * DD;
  #pragma unroll
  for (int kstep = 0; kstep < 4; ++kstep) {
    const float4* xp = (const float4*)(xr + klane + kstep * 32);
    float4 v0 = xp[0], v1 = xp[1];
    f16x8 a;
    a[0] = (_Float16)v0.x; a[1] = (_Float16)v0.y;
    a[2] = (_Float16)v0.z; a[3] = (_Float16)v0.w;
    a[4] = (_Float16)v1.x; a[5] = (_Float16)v1.y;
    a[6] = (_Float16)v1.z; a[7] = (_Float16)v1.w;
    #pragma unroll
    for (int ct = 0; ct < 4; ++ct) {
      f16x8 b = wfrag[(kstep * 8 + colgrp * 4 + ct) * 64 + lane];
      acc[ct] = __builtin_amdgcn_mfma_f32_16x16x32_f16(a, b, acc[ct], 0, 0, 0);
    }
  }
  // D layout: col = lane&15, row = (lane>>4)*4 + reg   [m89-verified]
  #pragma unroll
  for (int ct = 0; ct < 4; ++ct) {
    int col = colgrp * 64 + ct * 16 + (lane & 15);
    #pragma unroll
    for (int reg = 0; reg < 4; ++reg) {
      int r = rowbase + (lane >> 4) * 4 + reg;
      hW16[(size_t)r * DD + col] = __half_as_ushort(__float2half(acc[ct][reg]));
    }
  }
}

// ------- verify MFMA fragment layout on block-tile 0; flag on mismatch -------
__global__ void k_check(const float* __restrict__ x, const float* __restrict__ w,
                        const u16* __restrict__ hW16, u32* __restrict__ flag) {
  int idx = blockIdx.x * 256 + threadIdx.x; // 4096 = 32 rows x 128 cols
  int r = idx >> 7, c = idx & 127;
  float acc = 0.0f;
  for (int k = 0; k < DD; ++k) acc += x[r * DD + k] * w[k * DD + c];
  float got = __half2float(__ushort_as_half(hW16[r * DD + c]));
  if (fabsf(got - acc) > 0.02f) atomicOr(flag, 1u);
}

// ------- scalar fallback GEMM (runs only if MFMA layout check failed) -------
__global__ void k_gemm_fb(const float* __restrict__ x, const float* __restrict__ w,
                          u16* __restrict__ hW16, const u32* __restrict__ flag) {
  if (*flag == 0u) return;
  __shared__ float Wl[DD * DD]; // 64 KiB
  int t = threadIdx.x;
  for (int i = t; i < DD * DD; i += 256) Wl[i] = w[i];
  __syncthreads();
  int base = blockIdx.x * 16;
  int c = t & 127, rh = t >> 7;
  for (int it = 0; it < 8; ++it) {
    int r = base + it * 2 + rh;
    if (r < NN) {
      const float4* xr = (const float4*)(x + (size_t)r * DD);
      float acc = 0.0f;
      #pragma unroll 4
      for (int k4 = 0; k4 < 32; ++k4) {
        float4 xv = xr[k4];
        int kb = k4 * 4;
        acc += xv.x * Wl[kb * DD + c];
        acc += xv.y * Wl[(kb + 1) * DD + c];
        acc += xv.z * Wl[(kb + 2) * DD + c];
        acc += xv.w * Wl[(kb + 3) * DD + c];
      }
      hW16[(size_t)r * DD + c] = __half_as_ushort(__float2half(acc));
    }
  }
}

// ---- gather-aggregate (fp16 rows, f32 accum, unroll-4) + key + gate ----
// lane handles dims (2*lane, 2*lane+1): one u32 = half2 per lane per row.
__global__ void k_agg(const u32* __restrict__ hw, const float* __restrict__ dinv32,
                      const u32* __restrict__ offs, const u32* __restrict__ deg,
                      const int* __restrict__ csr, const float* __restrict__ bias,
                      float* __restrict__ hc, u64* __restrict__ key,
                      float* __restrict__ gate) {
  int node = blockIdx.x * 4 + (threadIdx.x >> 6);
  int lane = threadIdx.x & 63;
  if (node >= NN) return;
  float di = dinv32[node];
  float a0 = 0.0f, a1 = 0.0f;
  u32 o = offs[node], cnt = deg[node];
  u32 k = 0;
  for (; k + 4 <= cnt; k += 4) {
    int s0 = csr[o + k], s1 = csr[o + k + 1], s2 = csr[o + k + 2], s3 = csr[o + k + 3];
    float n0 = dinv32[s0] * di, n1 = dinv32[s1] * di;
    float n2 = dinv32[s2] * di, n3 = dinv32[s3] * di;
    u32 w0 = hw[(size_t)s0 * 64 + lane];
    u32 w1 = hw[(size_t)s1 * 64 + lane];
    u32 w2 = hw[(size_t)s2 * 64 + lane];
    u32 w3 = hw[(size_t)s3 * 64 + lane];
    float2 h0 = __half22float2(*(__half2*)&w0);
    float2 h1 = __half22float2(*(__half2*)&w1);
    float2 h2 = __half22float2(*(__half2*)&w2);
    float2 h3 = __half22float2(*(__half2*)&w3);
    a0 += h0.x * n0 + h1.x * n1 + h2.x * n2 + h3.x * n3;
    a1 += h0.y * n0 + h1.y * n1 + h2.y * n2 + h3.y * n3;
  }
  for (; k < cnt; ++k) {
    int s = csr[o + k];
    float nrm = dinv32[s] * di;
    u32 wb = hw[(size_t)s * 64 + lane];
    float2 hv = __half22float2(*(__half2*)&wb);
    a0 += hv.x * nrm;
    a1 += hv.y * nrm;
  }
  float di2 = di * di;
  u32 wb = hw[(size_t)node * 64 + lane];
  float2 hv = __half22float2(*(__half2*)&wb);
  float2 bv = ((const float2*)bias)[lane];
  a0 += hv.x * di2 + bv.x;
  a1 += hv.y * di2 + bv.y;
  ((float2*)hc)[(size_t)node * 64 + lane] = make_float2(a0, a1);
  float ss = a0 * a0 + a1 * a1;
  #pragma unroll
  for (int off = 32; off > 0; off >>= 1) ss += __shfl_xor(ss, off);
  if (lane == 0) {
    // approx key: f32 ss bits (monotone in score, ss >= 0);
    // low 17 bits = (0x1FFFF - node) => lower index wins ties
    u32 sb = __float_as_uint(ss);
    key[node] = ((u64)sb << 17) | (u64)(0x1FFFF - node);
    gate[node] = tanhf(sqrtf(ss + 1e-12f));
  }
}

// ---------------- exact bucket-rank (approx keys -> full rank) ----------------
__global__ void k_minmax(const u64* __restrict__ key, u64* __restrict__ meta) {
  __shared__ u64 smn[256], smx[256];
  int t = threadIdx.x; int i = blockIdx.x * 256 + t;
  u64 v = (i < NN) ? key[i] : key[0];
  smn[t] = v; smx[t] = v; __syncthreads();
  for (int s = 128; s > 0; s >>= 1) {
    if (t < s) {
      if (smn[t + s] < smn[t]) smn[t] = smn[t + s];
      if (smx[t + s] > smx[t]) smx[t] = smx[t + s];
    }
    __syncthreads();
  }
  if (t == 0) { atomicMin(&meta[0], smn[0]); atomicMax(&meta[1], smx[0]); }
}

__global__ void k_shift(u64* __restrict__ meta) {
  u64 range = meta[1] - meta[0];
  int bits = 64 - __clzll(range | 1ull);
  meta[2] = (u64)(bits > 17 ? bits - 17 : 0);
}

__global__ void k_hist(const u64* __restrict__ key, const u64* __restrict__ meta,
                       u32* __restrict__ barr, u32* __restrict__ bcnt) {
  int i = blockIdx.x * blockDim.x + threadIdx.x;
  if (i >= NN) return;
  u32 b = (u32)((key[i] - meta[0]) >> meta[2]);
  barr[i] = b;
  atomicAdd(&bcnt[b], 1u);
}

__global__ void k_bscan1(const u32* __restrict__ bcnt, u32* __restrict__ bsum2) {
  __shared__ u32 sh[256];
  int t = threadIdx.x; int r = blockIdx.x * 256 + t;
  u32 v = bcnt[NB - 1 - r];
  sh[t] = v; __syncthreads();
  for (int s = 128; s > 0; s >>= 1) { if (t < s) sh[t] += sh[t + s]; __syncthreads(); }
  if (t == 0) bsum2[blockIdx.x] = sh[0];
}

__global__ void k_bscan3(const u32* __restrict__ bcnt, const u32* __restrict__ bsum2,
                         u32* __restrict__ base, u32* __restrict__ bcur) {
  __shared__ u32 buf[2][256];
  int t = threadIdx.x; int r = blockIdx.x * 256 + t;
  int b = NB - 1 - r;
  u32 v = bcnt[b];
  int a = 0; buf[0][t] = v; __syncthreads();
  for (int s = 1; s < 256; s <<= 1) {
    buf[1 - a][t] = buf[a][t] + ((t >= s) ? buf[a][t - s] : 0u);
    a = 1 - a; __syncthreads();
  }
  u32 bs = buf[a][t] - v + bsum2[blockIdx.x]; // suffix-exclusive
  base[b] = bs;
  bcur[b] = NN - bs - v;
}

__global__ void k_bscatter(const u32* __restrict__ barr, u32* __restrict__ bcur,
                           u32* __restrict__ blist) {
  int i = blockIdx.x * blockDim.x + threadIdx.x;
  if (i >= NN) return;
  u32 p = atomicAdd(&bcur[barr[i]], 1u);
  blist[p] = (u32)i;
}

__global__ void k_rank2(const u64* __restrict__ key, const u32* __restrict__ barr,
                        const u32* __restrict__ bcnt, const u32* __restrict__ base,
                        const u32* __restrict__ blist, int* __restrict__ arank) {
  int i = blockIdx.x * blockDim.x + threadIdx.x;
  if (i >= NN) return;
  u32 b = barr[i];
  u64 ki = key[i];
  u32 bs = base[b], cnt = bcnt[b];
  u32 off = NN - bs - cnt;
  u32 gt = 0;
  for (u32 j = 0; j < cnt; ++j) gt += (key[blist[off + j]] > ki) ? 1u : 0u;
  arank[i] = (int)(bs + gt); // full approx rank (a permutation of 0..NN-1)
}

// ---------------- exact band repair ----------------
__global__ void k_bandsel(const int* __restrict__ arank, u32* __restrict__ bandNode) {
  int i = blockIdx.x * blockDim.x + threadIdx.x;
  if (i >= NN) return;
  int r = arank[i] - (KK - BB);
  if (r >= 0 && r < 2 * BB) bandNode[r] = (u32)i;
}

// exact f64 rescore via linearity: a = (sum_s wgt_s * x_s) @ W + bias
__global__ void k_bscore(const u32* __restrict__ bandNode,
                         const float* __restrict__ x, const float* __restrict__ w,
                         const double* __restrict__ dinv64,
                         const u32* __restrict__ offs, const u32* __restrict__ deg,
                         const int* __restrict__ csr, const float* __restrict__ bias,
                         u64* __restrict__ ekey) {
  __shared__ double zsh[4][DD]; // 4 KiB
  int wid = threadIdx.x >> 6;
  int lane = threadIdx.x & 63;
  int slot = blockIdx.x * 4 + wid;
  int node = (int)bandNode[slot];
  double di = dinv64[node];
  double z0 = 0.0, z1 = 0.0;
  u32 o = offs[node], cnt = deg[node];
  for (u32 k = 0; k <= cnt; ++k) { // last iter = self row
    int s = (k < cnt) ? csr[o + k] : node;
    double wgt = (k < cnt) ? (dinv64[s] * di) : (di * di);
    float2 xv = ((const float2*)x)[(size_t)s * 64 + lane];
    z0 += (double)xv.x * wgt;
    z1 += (double)xv.y * wgt;
  }
  zsh[wid][2 * lane] = z0;
  zsh[wid][2 * lane + 1] = z1;
  __syncthreads();
  float2 bv = ((const float2*)bias)[lane];
  double a0 = (double)bv.x, a1 = (double)bv.y;
  for (int kk = 0; kk < DD; ++kk) {
    double zk = zsh[wid][kk];
    float2 wv = ((const float2*)w)[kk * 64 + lane];
    a0 += zk * (double)wv.x;
    a1 += zk * (double)wv.y;
  }
  double ss = a0 * a0 + a1 * a1;
  #pragma unroll
  for (int off = 32; off > 0; off >>= 1) ss += __shfl_xor(ss, off);
  if (lane == 0) {
    double sc = sqrt(ss + 1e-12);
    u64 bits = (u64)__double_as_longlong(sc);
    ekey[slot] = (bits & ~0x1FFFFull) | (u64)(0x1FFFF - node);
  }
}

__global__ void k_bandrank(const u64* __restrict__ ekey, u32* __restrict__ brank) {
  __shared__ u64 sk[2 * BB]; // 32 KiB
  int t = threadIdx.x;
  for (int j = t; j < 2 * BB; j += 256) sk[j] = ekey[j];
  __syncthreads();
  int idx = blockIdx.x * 256 + t;
  u64 kk = sk[idx];
  u32 c = 0;
  for (int j = 0; j < 2 * BB; ++j) c += (sk[j] > kk) ? 1u : 0u;
  brank[idx] = c;
}

__global__ void k_pos2(const int* __restrict__ arank, const u32* __restrict__ brank,
                       int* __restrict__ pos) {
  int i = blockIdx.x * blockDim.x + threadIdx.x;
  if (i >= NN) return;
  int r = arank[i];
  int p;
  if (r < KK - BB) p = r;                       // surely kept
  else if (r < KK + BB) {                       // band: exact order decides
    u32 br = brank[r - (KK - BB)];
    p = (br < BB) ? (KK - BB + (int)br) : -1;
  } else p = -1;                                // surely dropped
  pos[i] = p;
}

// ---------------- outputs (f32, bf16-RNE-quantized) ----------------
__global__ void k_xout(const float* __restrict__ hc, const float* __restrict__ gate,
                       const int* __restrict__ pos, float* __restrict__ outx) {
  int id = blockIdx.x * blockDim.x + threadIdx.x;
  if (id >= NN * DD) return;
  int i = id >> 7, d = id & 127;
  int p = pos[i];
  if (p < 0) return;
  float v = hc[(size_t)i * DD + d] * gate[i];
  outx[(size_t)p * DD + d] = bq(v);
}

__global__ void k_edges(const int* __restrict__ ei, const int* __restrict__ pos,
                        float* __restrict__ osrc, float* __restrict__ odst,
                        float* __restrict__ omask) {
  int e = blockIdx.x * blockDim.x + threadIdx.x;
  if (e >= EE) return;
  int ns = pos[ei[e]];
  int nd = pos[ei[EE + e]];
  bool m = (ns >= 0) && (nd >= 0);
  osrc[e] = m ? bq((float)ns) : -1.0f;
  odst[e] = m ? bq((float)nd) : -1.0f;
  omask[e] = m ? 1.0f : 0.0f;
}

// ---------------- driver ----------------
extern "C" void kernel_launch(void* const* d_in, const int* in_sizes, int n_in,
                              void* d_out, int out_size, void* d_ws, size_t ws_size,
                              hipStream_t stream) {
  const float* x    = (const float*)d_in[0];
  const int*   ei   = (const int*)d_in[1];
  const float* w    = (const float*)d_in[2];
  const float* bias = (const float*)d_in[3];
  float* outx = (float*)d_out;
  char* ws = (char*)d_ws;

  size_t off = 0;
  auto alloc = [&](size_t b) -> void* {
    void* p = ws + off; off += (b + 255) & ~(size_t)255; return p;
  };
  u16*    hW16   = (u16*)alloc((size_t)NN * DD * 2);
  float*  hc     = (float*)alloc((size_t)NN * DD * 4);
  double* dinv64 = (double*)alloc((size_t)NN * 8);
  float*  dinv32 = (float*)alloc((size_t)NN * 4);
  float*  gate   = (float*)alloc((size_t)NN * 4);
  u64*    key    = (u64*)alloc((size_t)NN * 8);
  u32*    deg    = (u32*)alloc((size_t)NN * 4);
  u32*    offs   = (u32*)alloc((size_t)NN * 4);
  u32*    cur    = (u32*)alloc((size_t)NN * 4);
  int*    csr    = (int*)alloc((size_t)EE * 4);
  int*    arank  = (int*)alloc((size_t)NN * 4);
  int*    pos    = (int*)alloc((size_t)NN * 4);
  u32*    bsum   = (u32*)alloc(512 * 4);
  u64*    meta   = (u64*)alloc(4 * 8);
  u32*    bcnt   = (u32*)alloc((size_t)NB * 4);
  u32*    base   = (u32*)alloc((size_t)NB * 4);
  u32*    bcur   = (u32*)alloc((size_t)NB * 4);
  u32*    bsum2  = (u32*)alloc(SBLK * 4);
  u32*    barr   = (u32*)alloc((size_t)NN * 4);
  u32*    blist  = (u32*)alloc((size_t)NN * 4);
  u32*    bandNode = (u32*)alloc((size_t)2 * BB * 4);
  u64*    ekey     = (u64*)alloc((size_t)2 * BB * 8);
  u32*    brank    = (u32*)alloc((size_t)2 * BB * 4);
  f16x8*  wfrag    = (f16x8*)alloc((size_t)2048 * 16);
  u32*    mflag    = (u32*)alloc(256);

  hipMemsetAsync(deg, 0, (size_t)NN * 4, stream);
  hipMemsetAsync(bcnt, 0, (size_t)NB * 4, stream);
  hipMemsetAsync(meta, 0xFF, 8, stream);      // kmin = ~0
  hipMemsetAsync(meta + 1, 0x00, 8, stream);  // kmax = 0
  hipMemsetAsync(mflag, 0, 4, stream);

  k_deg<<<(EE + 255) / 256, 256, 0, stream>>>(ei, deg);
  k_dinv<<<(NN + 255) / 256, 256, 0, stream>>>(deg, dinv64, dinv32);
  k_scan1<<<IBLK, 256, 0, stream>>>(deg, bsum);
  k_scan2<<<1, 512, 0, stream>>>(bsum, IBLK);
  k_scan3<<<IBLK, 256, 0, stream>>>(deg, bsum, offs, cur);
  k_scatter<<<(EE + 255) / 256, 256, 0, stream>>>(ei, cur, csr);
  // GEMM: MFMA main path + layout self-check + scalar fallback
  k_wfrag<<<8, 256, 0, stream>>>(w, wfrag);
  k_gemm_mfma<<<NN / 32, 256, 0, stream>>>(x, wfrag, hW16);
  k_check<<<16, 256, 0, stream>>>(x, w, hW16, mflag);
  k_gemm_fb<<<(NN + 15) / 16, 256, 0, stream>>>(x, w, hW16, mflag);
  k_agg<<<(NN + 3) / 4, 256, 0, stream>>>((const u32*)hW16, dinv32, offs, deg, csr,
                                          bias, hc, key, gate);
  k_minmax<<<IBLK, 256, 0, stream>>>(key, meta);
  k_shift<<<1, 1, 0, stream>>>(meta);
  k_hist<<<(NN + 255) / 256, 256, 0, stream>>>(key, meta, barr, bcnt);
  k_bscan1<<<SBLK, 256, 0, stream>>>(bcnt, bsum2);
  k_scan2<<<1, 512, 0, stream>>>(bsum2, SBLK);
  k_bscan3<<<SBLK, 256, 0, stream>>>(bcnt, bsum2, base, bcur);
  k_bscatter<<<(NN + 255) / 256, 256, 0, stream>>>(barr, bcur, blist);
  k_rank2<<<(NN + 255) / 256, 256, 0, stream>>>(key, barr, bcnt, base, blist, arank);
  // exact band repair (f64 truth via linearity)
  k_bandsel<<<(NN + 255) / 256, 256, 0, stream>>>(arank, bandNode);
  k_bscore<<<(2 * BB) / 4, 256, 0, stream>>>(bandNode, x, w, dinv64, offs, deg, csr,
                                             bias, ekey);
  k_bandrank<<<(2 * BB) / 256, 256, 0, stream>>>(ekey, brank);
  k_pos2<<<(NN + 255) / 256, 256, 0, stream>>>(arank, brank, pos);
  k_xout<<<(NN * DD + 255) / 256, 256, 0, stream>>>(hc, gate, pos, outx);
  float* oei = outx + (size_t)KK * DD;
  k_edges<<<(EE + 255) / 256, 256, 0, stream>>>(ei, pos, oei, oei + EE, oei + 2 * (size_t)EE);
}

// Round 7
// 557.829 us; speedup vs baseline: 3.5886x; 1.3959x over previous
//
#include <hip/hip_runtime.h>
#include <hip/hip_fp16.h>
#include <stdint.h>

#define NN 100000
#define EE 3200000
#define DD 128
#define KK 50000
#define NB 131072   // rank buckets (2^17)
#define SBLK 512    // NB / 256
#define BB 2048     // band half-width around rank K (band size 2*BB)
#define NBK 391     // coarse edge buckets (256 dst nodes each)
#define TILE 8192   // edges per k_part1 block
#define BMAX 12288  // max edges per coarse bucket staged in LDS (14 sigma)

using u16 = unsigned short;
using u32 = unsigned int;
using u64 = unsigned long long;

typedef _Float16 f16x8 __attribute__((ext_vector_type(8)));
typedef float f32x4 __attribute__((ext_vector_type(4)));

// f32 -> bf16(RNE) -> f32, matching the harness's bf16-quantized reference.
__device__ __forceinline__ float bq(float f) {
  u32 b = __float_as_uint(f);
  b += 0x7FFFu + ((b >> 16) & 1u);
  return __uint_as_float(b & 0xFFFF0000u);
}

// ---------------- degree histogram ----------------
__global__ void k_deg(const int* __restrict__ ei, u32* __restrict__ deg) {
  int e = blockIdx.x * blockDim.x + threadIdx.x;
  if (e < EE) atomicAdd(&deg[ei[EE + e]], 1u);
}

__global__ void k_dinv(const u32* __restrict__ deg, double* __restrict__ dinv64,
                       float* __restrict__ dinv32) {
  int i = blockIdx.x * blockDim.x + threadIdx.x;
  if (i < NN) {
    double d = 1.0 / sqrt((double)(deg[i] + 1u)); // +1 self-loop
    dinv64[i] = d;
    dinv32[i] = (float)d;
  }
}

// ---------------- CSR offsets: 3-kernel scan ----------------
#define IBLK 391

__global__ void k_scan1(const u32* __restrict__ deg, u32* __restrict__ bsum) {
  __shared__ u32 sh[256];
  int t = threadIdx.x; int i = blockIdx.x * 256 + t;
  u32 v = (i < NN) ? deg[i] : 0u;
  sh[t] = v; __syncthreads();
  for (int s = 128; s > 0; s >>= 1) { if (t < s) sh[t] += sh[t + s]; __syncthreads(); }
  if (t == 0) bsum[blockIdx.x] = sh[0];
}

__global__ void k_scan2(u32* __restrict__ bsum, int nb) { // 1 block, 512 thr, nb<=512
  __shared__ u32 buf[2][512];
  int t = threadIdx.x;
  u32 v = (t < nb) ? bsum[t] : 0u;
  int a = 0; buf[0][t] = v; __syncthreads();
  for (int s = 1; s < 512; s <<= 1) {
    buf[1 - a][t] = buf[a][t] + ((t >= s) ? buf[a][t - s] : 0u);
    a = 1 - a; __syncthreads();
  }
  if (t < nb) bsum[t] = buf[a][t] - v; // exclusive
}

__global__ void k_scan3(const u32* __restrict__ deg, const u32* __restrict__ bsum,
                        u32* __restrict__ offs, u32* __restrict__ cur) {
  __shared__ u32 buf[2][256];
  int t = threadIdx.x; int i = blockIdx.x * 256 + t;
  u32 v = (i < NN) ? deg[i] : 0u;
  int a = 0; buf[0][t] = v; __syncthreads();
  for (int s = 1; s < 256; s <<= 1) {
    buf[1 - a][t] = buf[a][t] + ((t >= s) ? buf[a][t - s] : 0u);
    a = 1 - a; __syncthreads();
  }
  if (i < NN) {
    u32 exc = buf[a][t] - v + bsum[blockIdx.x];
    offs[i] = exc; cur[i] = exc;
  }
}

// ---------------- CSR build: two-pass LDS-staged partition ----------------
// (replaces the random-scatter k_scatter whose 4B stores cost 64B/line writebacks)
__global__ void k_binit(const u32* __restrict__ offs, u32* __restrict__ bcur) {
  int b = blockIdx.x * 256 + threadIdx.x;
  if (b < NBK) bcur[b] = offs[b * 256];
}

// pass 1: partition edges into 391 coarse buckets (coalesced run flushes)
__global__ void k_part1(const int* __restrict__ ei, u32* __restrict__ bcur,
                        u32* __restrict__ ebuf) {
  __shared__ u32 cnt[NBK];
  __shared__ u32 lpos[NBK];
  __shared__ u32 gbase[NBK];
  __shared__ u32 sbuf[TILE];  // 32 KiB packed entries, bucket-sorted
  __shared__ u16 sbid[TILE];  // 16 KiB bucket id per slot
  int t = threadIdx.x;
  int e0 = blockIdx.x * TILE;
  int vcnt = EE - e0; if (vcnt > TILE) vcnt = TILE;
  for (int i = t; i < NBK; i += 256) cnt[i] = 0;
  __syncthreads();
  for (int i = t; i < vcnt; i += 256) {
    int d = ei[EE + e0 + i];
    atomicAdd(&cnt[d >> 8], 1u);
  }
  __syncthreads();
  // exclusive scan cnt -> lpos (wave 0, shfl segments of 64)
  if (t < 64) {
    u32 carry = 0;
    for (int c = 0; c < 7; ++c) {
      int idx = c * 64 + t;
      u32 v = (idx < NBK) ? cnt[idx] : 0u;
      u32 x = v;
      #pragma unroll
      for (int s = 1; s < 64; s <<= 1) {
        u32 y = __shfl_up(x, s);
        if (t >= s) x += y;
      }
      if (idx < NBK) lpos[idx] = x - v + carry;
      carry += __shfl(x, 63);
    }
  }
  __syncthreads();
  for (int i = t; i < NBK; i += 256)
    gbase[i] = cnt[i] ? atomicAdd(&bcur[i], cnt[i]) : 0u;
  // local scatter (bucket-sorted within the tile)
  for (int i = t; i < vcnt; i += 256) {
    int d = ei[EE + e0 + i];
    int s = ei[e0 + i];
    u32 b = (u32)d >> 8;
    u32 p = atomicAdd(&lpos[b], 1u);
    sbuf[p] = ((u32)(d & 255) << 17) | (u32)s;
    sbid[p] = (u16)b;
  }
  __syncthreads();
  // coalesced run flush
  for (int i = t; i < vcnt; i += 256) {
    u32 b = sbid[i];
    u32 lstart = lpos[b] - cnt[b];
    ebuf[gbase[b] + ((u32)i - lstart)] = sbuf[i];
  }
}

// pass 2: within each bucket, exact csr positions via LDS cursors, coalesced out
__global__ void k_part2(const u32* __restrict__ ebuf, const u32* __restrict__ offs,
                        u32* __restrict__ cur, int* __restrict__ csr) {
  __shared__ u32 ncur[256];
  __shared__ u32 scsr[BMAX]; // 48 KiB
  int b = blockIdx.x; int t = threadIdx.x;
  int nbase = b * 256;
  u32 gstart = offs[nbase];
  u32 gend = (nbase + 256 < NN) ? offs[nbase + 256] : (u32)EE;
  u32 cnt = gend - gstart;
  if (nbase + t < NN) ncur[t] = offs[nbase + t] - gstart;
  __syncthreads();
  if (cnt <= (u32)BMAX) {
    for (u32 i = t; i < cnt; i += 256) {
      u32 en = ebuf[gstart + i];
      u32 p = atomicAdd(&ncur[en >> 17], 1u);
      scsr[p] = en & 0x1FFFFu;
    }
    __syncthreads();
    for (u32 i = t; i < cnt; i += 256) csr[gstart + i] = (int)scsr[i];
  } else { // statistically unreachable fallback: direct global scatter
    for (u32 i = t; i < cnt; i += 256) {
      u32 en = ebuf[gstart + i];
      u32 p = atomicAdd(&cur[nbase + (en >> 17)], 1u);
      csr[p] = (int)(en & 0x1FFFFu);
    }
  }
}

// ------- W -> per-lane f16 MFMA fragments -------
// wfrag[(kstep*8 + ctt)*64 + lane] = B[k][c], k=(lane>>4)*8+j+kstep*32, c=ctt*16+(lane&15)
__global__ void k_wfrag(const float* __restrict__ w, f16x8* __restrict__ wfrag) {
  int idx = blockIdx.x * 256 + threadIdx.x; // 2048 total
  int lane = idx & 63;
  int ctt = (idx >> 6) & 7;
  int kstep = idx >> 9;
  int c = ctt * 16 + (lane & 15);
  int kbase = (lane >> 4) * 8 + kstep * 32;
  f16x8 v;
  #pragma unroll
  for (int j = 0; j < 8; ++j) v[j] = (_Float16)w[(kbase + j) * DD + c];
  wfrag[idx] = v;
}

// ------- h = x @ W via MFMA 16x16x32 f16 (f32 accumulate, emit fp16) -------
__global__ void __launch_bounds__(256) k_gemm_mfma(const float* __restrict__ x,
                                                   const f16x8* __restrict__ wfrag,
                                                   u16* __restrict__ hW16) {
  int wid = threadIdx.x >> 6, lane = threadIdx.x & 63;
  int rowbase = blockIdx.x * 32 + (wid & 1) * 16;
  int colgrp = wid >> 1; // 0..1, 64 cols each
  int row = rowbase + (lane & 15);
  int klane = (lane >> 4) * 8;

  f32x4 acc[4] = {{0,0,0,0},{0,0,0,0},{0,0,0,0},{0,0,0,0}};
  const float* xr = x + (size_t)row * DD;
  #pragma unroll
  for (int kstep = 0; kstep < 4; ++kstep) {
    const float4* xp = (const float4*)(xr + klane + kstep * 32);
    float4 v0 = xp[0], v1 = xp[1];
    f16x8 a;
    a[0] = (_Float16)v0.x; a[1] = (_Float16)v0.y;
    a[2] = (_Float16)v0.z; a[3] = (_Float16)v0.w;
    a[4] = (_Float16)v1.x; a[5] = (_Float16)v1.y;
    a[6] = (_Float16)v1.z; a[7] = (_Float16)v1.w;
    #pragma unroll
    for (int ct = 0; ct < 4; ++ct) {
      f16x8 b = wfrag[(kstep * 8 + colgrp * 4 + ct) * 64 + lane];
      acc[ct] = __builtin_amdgcn_mfma_f32_16x16x32_f16(a, b, acc[ct], 0, 0, 0);
    }
  }
  // D layout: col = lane&15, row = (lane>>4)*4 + reg   [m89-verified]
  #pragma unroll
  for (int ct = 0; ct < 4; ++ct) {
    int col = colgrp * 64 + ct * 16 + (lane & 15);
    #pragma unroll
    for (int reg = 0; reg < 4; ++reg) {
      int r = rowbase + (lane >> 4) * 4 + reg;
      hW16[(size_t)r * DD + col] = __half_as_ushort(__float2half(acc[ct][reg]));
    }
  }
}

// ------- verify MFMA fragment layout on block-tile 0; flag on mismatch -------
__global__ void k_check(const float* __restrict__ x, const float* __restrict__ w,
                        const u16* __restrict__ hW16, u32* __restrict__ flag) {
  int idx = blockIdx.x * 256 + threadIdx.x; // 4096 = 32 rows x 128 cols
  int r = idx >> 7, c = idx & 127;
  float acc = 0.0f;
  for (int k = 0; k < DD; ++k) acc += x[r * DD + k] * w[k * DD + c];
  float got = __half2float(__ushort_as_half(hW16[r * DD + c]));
  if (fabsf(got - acc) > 0.02f) atomicOr(flag, 1u);
}

// ------- scalar fallback GEMM (runs only if MFMA layout check failed) -------
__global__ void k_gemm_fb(const float* __restrict__ x, const float* __restrict__ w,
                          u16* __restrict__ hW16, const u32* __restrict__ flag) {
  if (*flag == 0u) return;
  __shared__ float Wl[DD * DD]; // 64 KiB
  int t = threadIdx.x;
  for (int i = t; i < DD * DD; i += 256) Wl[i] = w[i];
  __syncthreads();
  int base = blockIdx.x * 16;
  int c = t & 127, rh = t >> 7;
  for (int it = 0; it < 8; ++it) {
    int r = base + it * 2 + rh;
    if (r < NN) {
      const float4* xr = (const float4*)(x + (size_t)r * DD);
      float acc = 0.0f;
      #pragma unroll 4
      for (int k4 = 0; k4 < 32; ++k4) {
        float4 xv = xr[k4];
        int kb = k4 * 4;
        acc += xv.x * Wl[kb * DD + c];
        acc += xv.y * Wl[(kb + 1) * DD + c];
        acc += xv.z * Wl[(kb + 2) * DD + c];
        acc += xv.w * Wl[(kb + 3) * DD + c];
      }
      hW16[(size_t)r * DD + c] = __half_as_ushort(__float2half(acc));
    }
  }
}

// ---- gather-aggregate (fp16 rows, f32 accum, unroll-4) + key + gate ----
// lane handles dims (2*lane, 2*lane+1): one u32 = half2 per lane per row.
__global__ void k_agg(const u32* __restrict__ hw, const float* __restrict__ dinv32,
                      const u32* __restrict__ offs, const u32* __restrict__ deg,
                      const int* __restrict__ csr, const float* __restrict__ bias,
                      float* __restrict__ hc, u64* __restrict__ key,
                      float* __restrict__ gate) {
  int node = blockIdx.x * 4 + (threadIdx.x >> 6);
  int lane = threadIdx.x & 63;
  if (node >= NN) return;
  float di = dinv32[node];
  float a0 = 0.0f, a1 = 0.0f;
  u32 o = offs[node], cnt = deg[node];
  u32 k = 0;
  for (; k + 4 <= cnt; k += 4) {
    int s0 = csr[o + k], s1 = csr[o + k + 1], s2 = csr[o + k + 2], s3 = csr[o + k + 3];
    float n0 = dinv32[s0] * di, n1 = dinv32[s1] * di;
    float n2 = dinv32[s2] * di, n3 = dinv32[s3] * di;
    u32 w0 = hw[(size_t)s0 * 64 + lane];
    u32 w1 = hw[(size_t)s1 * 64 + lane];
    u32 w2 = hw[(size_t)s2 * 64 + lane];
    u32 w3 = hw[(size_t)s3 * 64 + lane];
    float2 h0 = __half22float2(*(__half2*)&w0);
    float2 h1 = __half22float2(*(__half2*)&w1);
    float2 h2 = __half22float2(*(__half2*)&w2);
    float2 h3 = __half22float2(*(__half2*)&w3);
    a0 += h0.x * n0 + h1.x * n1 + h2.x * n2 + h3.x * n3;
    a1 += h0.y * n0 + h1.y * n1 + h2.y * n2 + h3.y * n3;
  }
  for (; k < cnt; ++k) {
    int s = csr[o + k];
    float nrm = dinv32[s] * di;
    u32 wb = hw[(size_t)s * 64 + lane];
    float2 hv = __half22float2(*(__half2*)&wb);
    a0 += hv.x * nrm;
    a1 += hv.y * nrm;
  }
  float di2 = di * di;
  u32 wb = hw[(size_t)node * 64 + lane];
  float2 hv = __half22float2(*(__half2*)&wb);
  float2 bv = ((const float2*)bias)[lane];
  a0 += hv.x * di2 + bv.x;
  a1 += hv.y * di2 + bv.y;
  ((float2*)hc)[(size_t)node * 64 + lane] = make_float2(a0, a1);
  float ss = a0 * a0 + a1 * a1;
  #pragma unroll
  for (int off = 32; off > 0; off >>= 1) ss += __shfl_xor(ss, off);
  if (lane == 0) {
    // approx key: f32 ss bits (monotone in score, ss >= 0);
    // low 17 bits = (0x1FFFF - node) => lower index wins ties
    u32 sb = __float_as_uint(ss);
    key[node] = ((u64)sb << 17) | (u64)(0x1FFFF - node);
    gate[node] = tanhf(sqrtf(ss + 1e-12f));
  }
}

// ---------------- exact bucket-rank (approx keys -> full rank) ----------------
__global__ void k_minmax(const u64* __restrict__ key, u64* __restrict__ meta) {
  __shared__ u64 smn[256], smx[256];
  int t = threadIdx.x; int i = blockIdx.x * 256 + t;
  u64 v = (i < NN) ? key[i] : key[0];
  smn[t] = v; smx[t] = v; __syncthreads();
  for (int s = 128; s > 0; s >>= 1) {
    if (t < s) {
      if (smn[t + s] < smn[t]) smn[t] = smn[t + s];
      if (smx[t + s] > smx[t]) smx[t] = smx[t + s];
    }
    __syncthreads();
  }
  if (t == 0) { atomicMin(&meta[0], smn[0]); atomicMax(&meta[1], smx[0]); }
}

__global__ void k_shift(u64* __restrict__ meta) {
  u64 range = meta[1] - meta[0];
  int bits = 64 - __clzll(range | 1ull);
  meta[2] = (u64)(bits > 17 ? bits - 17 : 0);
}

__global__ void k_hist(const u64* __restrict__ key, const u64* __restrict__ meta,
                       u32* __restrict__ barr, u32* __restrict__ bcnt) {
  int i = blockIdx.x * blockDim.x + threadIdx.x;
  if (i >= NN) return;
  u32 b = (u32)((key[i] - meta[0]) >> meta[2]);
  barr[i] = b;
  atomicAdd(&bcnt[b], 1u);
}

__global__ void k_bscan1(const u32* __restrict__ bcnt, u32* __restrict__ bsum2) {
  __shared__ u32 sh[256];
  int t = threadIdx.x; int r = blockIdx.x * 256 + t;
  u32 v = bcnt[NB - 1 - r];
  sh[t] = v; __syncthreads();
  for (int s = 128; s > 0; s >>= 1) { if (t < s) sh[t] += sh[t + s]; __syncthreads(); }
  if (t == 0) bsum2[blockIdx.x] = sh[0];
}

__global__ void k_bscan3(const u32* __restrict__ bcnt, const u32* __restrict__ bsum2,
                         u32* __restrict__ base, u32* __restrict__ bcur) {
  __shared__ u32 buf[2][256];
  int t = threadIdx.x; int r = blockIdx.x * 256 + t;
  int b = NB - 1 - r;
  u32 v = bcnt[b];
  int a = 0; buf[0][t] = v; __syncthreads();
  for (int s = 1; s < 256; s <<= 1) {
    buf[1 - a][t] = buf[a][t] + ((t >= s) ? buf[a][t - s] : 0u);
    a = 1 - a; __syncthreads();
  }
  u32 bs = buf[a][t] - v + bsum2[blockIdx.x]; // suffix-exclusive
  base[b] = bs;
  bcur[b] = NN - bs - v;
}

__global__ void k_bscatter(const u32* __restrict__ barr, u32* __restrict__ bcur,
                           u32* __restrict__ blist) {
  int i = blockIdx.x * blockDim.x + threadIdx.x;
  if (i >= NN) return;
  u32 p = atomicAdd(&bcur[barr[i]], 1u);
  blist[p] = (u32)i;
}

__global__ void k_rank2(const u64* __restrict__ key, const u32* __restrict__ barr,
                        const u32* __restrict__ bcnt, const u32* __restrict__ base,
                        const u32* __restrict__ blist, int* __restrict__ arank) {
  int i = blockIdx.x * blockDim.x + threadIdx.x;
  if (i >= NN) return;
  u32 b = barr[i];
  u64 ki = key[i];
  u32 bs = base[b], cnt = bcnt[b];
  u32 off = NN - bs - cnt;
  u32 gt = 0;
  for (u32 j = 0; j < cnt; ++j) gt += (key[blist[off + j]] > ki) ? 1u : 0u;
  arank[i] = (int)(bs + gt); // full approx rank (a permutation of 0..NN-1)
}

// ---------------- exact band repair ----------------
__global__ void k_bandsel(const int* __restrict__ arank, u32* __restrict__ bandNode) {
  int i = blockIdx.x * blockDim.x + threadIdx.x;
  if (i >= NN) return;
  int r = arank[i] - (KK - BB);
  if (r >= 0 && r < 2 * BB) bandNode[r] = (u32)i;
}

// exact f64 rescore via linearity: a = (sum_s wgt_s * x_s) @ W + bias
__global__ void k_bscore(const u32* __restrict__ bandNode,
                         const float* __restrict__ x, const float* __restrict__ w,
                         const double* __restrict__ dinv64,
                         const u32* __restrict__ offs, const u32* __restrict__ deg,
                         const int* __restrict__ csr, const float* __restrict__ bias,
                         u64* __restrict__ ekey) {
  __shared__ double zsh[4][DD]; // 4 KiB
  int wid = threadIdx.x >> 6;
  int lane = threadIdx.x & 63;
  int slot = blockIdx.x * 4 + wid;
  int node = (int)bandNode[slot];
  double di = dinv64[node];
  double z0 = 0.0, z1 = 0.0;
  u32 o = offs[node], cnt = deg[node];
  for (u32 k = 0; k <= cnt; ++k) { // last iter = self row
    int s = (k < cnt) ? csr[o + k] : node;
    double wgt = (k < cnt) ? (dinv64[s] * di) : (di * di);
    float2 xv = ((const float2*)x)[(size_t)s * 64 + lane];
    z0 += (double)xv.x * wgt;
    z1 += (double)xv.y * wgt;
  }
  zsh[wid][2 * lane] = z0;
  zsh[wid][2 * lane + 1] = z1;
  __syncthreads();
  float2 bv = ((const float2*)bias)[lane];
  double a0 = (double)bv.x, a1 = (double)bv.y;
  for (int kk = 0; kk < DD; ++kk) {
    double zk = zsh[wid][kk];
    float2 wv = ((const float2*)w)[kk * 64 + lane];
    a0 += zk * (double)wv.x;
    a1 += zk * (double)wv.y;
  }
  double ss = a0 * a0 + a1 * a1;
  #pragma unroll
  for (int off = 32; off > 0; off >>= 1) ss += __shfl_xor(ss, off);
  if (lane == 0) {
    double sc = sqrt(ss + 1e-12);
    u64 bits = (u64)__double_as_longlong(sc);
    ekey[slot] = (bits & ~0x1FFFFull) | (u64)(0x1FFFF - node);
  }
}

__global__ void k_bandrank(const u64* __restrict__ ekey, u32* __restrict__ brank) {
  __shared__ u64 sk[2 * BB]; // 32 KiB
  int t = threadIdx.x;
  for (int j = t; j < 2 * BB; j += 256) sk[j] = ekey[j];
  __syncthreads();
  int idx = blockIdx.x * 256 + t;
  u64 kk = sk[idx];
  u32 c = 0;
  for (int j = 0; j < 2 * BB; ++j) c += (sk[j] > kk) ? 1u : 0u;
  brank[idx] = c;
}

__global__ void k_pos2(const int* __restrict__ arank, const u32* __restrict__ brank,
                       int* __restrict__ pos) {
  int i = blockIdx.x * blockDim.x + threadIdx.x;
  if (i >= NN) return;
  int r = arank[i];
  int p;
  if (r < KK - BB) p = r;                       // surely kept
  else if (r < KK + BB) {                       // band: exact order decides
    u32 br = brank[r - (KK - BB)];
    p = (br < BB) ? (KK - BB + (int)br) : -1;
  } else p = -1;                                // surely dropped
  pos[i] = p;
}

// ---------------- outputs (f32, bf16-RNE-quantized) ----------------
__global__ void k_xout(const float* __restrict__ hc, const float* __restrict__ gate,
                       const int* __restrict__ pos, float* __restrict__ outx) {
  int id = blockIdx.x * blockDim.x + threadIdx.x;
  if (id >= NN * DD) return;
  int i = id >> 7, d = id & 127;
  int p = pos[i];
  if (p < 0) return;
  float v = hc[(size_t)i * DD + d] * gate[i];
  outx[(size_t)p * DD + d] = bq(v);
}

__global__ void k_edges(const int* __restrict__ ei, const int* __restrict__ pos,
                        float* __restrict__ osrc, float* __restrict__ odst,
                        float* __restrict__ omask) {
  int e = blockIdx.x * blockDim.x + threadIdx.x;
  if (e >= EE) return;
  int ns = pos[ei[e]];
  int nd = pos[ei[EE + e]];
  bool m = (ns >= 0) && (nd >= 0);
  osrc[e] = m ? bq((float)ns) : -1.0f;
  odst[e] = m ? bq((float)nd) : -1.0f;
  omask[e] = m ? 1.0f : 0.0f;
}

// ---------------- driver ----------------
extern "C" void kernel_launch(void* const* d_in, const int* in_sizes, int n_in,
                              void* d_out, int out_size, void* d_ws, size_t ws_size,
                              hipStream_t stream) {
  const float* x    = (const float*)d_in[0];
  const int*   ei   = (const int*)d_in[1];
  const float* w    = (const float*)d_in[2];
  const float* bias = (const float*)d_in[3];
  float* outx = (float*)d_out;
  char* ws = (char*)d_ws;

  size_t off = 0;
  auto alloc = [&](size_t b) -> void* {
    void* p = ws + off; off += (b + 255) & ~(size_t)255; return p;
  };
  u16*    hW16   = (u16*)alloc((size_t)NN * DD * 2);
  float*  hc     = (float*)alloc((size_t)NN * DD * 4);
  double* dinv64 = (double*)alloc((size_t)NN * 8);
  float*  dinv32 = (float*)alloc((size_t)NN * 4);
  float*  gate   = (float*)alloc((size_t)NN * 4);
  u64*    key    = (u64*)alloc((size_t)NN * 8);
  u32*    deg    = (u32*)alloc((size_t)NN * 4);
  u32*    offs   = (u32*)alloc((size_t)NN * 4);
  u32*    cur    = (u32*)alloc((size_t)NN * 4);
  int*    csr    = (int*)alloc((size_t)EE * 4);
  u32*    ebuf   = (u32*)alloc((size_t)EE * 4);
  u32*    pbcur  = (u32*)alloc((size_t)NBK * 4);
  int*    arank  = (int*)alloc((size_t)NN * 4);
  int*    pos    = (int*)alloc((size_t)NN * 4);
  u32*    bsum   = (u32*)alloc(512 * 4);
  u64*    meta   = (u64*)alloc(4 * 8);
  u32*    bcnt   = (u32*)alloc((size_t)NB * 4);
  u32*    base   = (u32*)alloc((size_t)NB * 4);
  u32*    bcur   = (u32*)alloc((size_t)NB * 4);
  u32*    bsum2  = (u32*)alloc(SBLK * 4);
  u32*    barr   = (u32*)alloc((size_t)NN * 4);
  u32*    blist  = (u32*)alloc((size_t)NN * 4);
  u32*    bandNode = (u32*)alloc((size_t)2 * BB * 4);
  u64*    ekey     = (u64*)alloc((size_t)2 * BB * 8);
  u32*    brank    = (u32*)alloc((size_t)2 * BB * 4);
  f16x8*  wfrag    = (f16x8*)alloc((size_t)2048 * 16);
  u32*    mflag    = (u32*)alloc(256);

  hipMemsetAsync(deg, 0, (size_t)NN * 4, stream);
  hipMemsetAsync(bcnt, 0, (size_t)NB * 4, stream);
  hipMemsetAsync(meta, 0xFF, 8, stream);      // kmin = ~0
  hipMemsetAsync(meta + 1, 0x00, 8, stream);  // kmax = 0
  hipMemsetAsync(mflag, 0, 4, stream);

  k_deg<<<(EE + 255) / 256, 256, 0, stream>>>(ei, deg);
  k_dinv<<<(NN + 255) / 256, 256, 0, stream>>>(deg, dinv64, dinv32);
  k_scan1<<<IBLK, 256, 0, stream>>>(deg, bsum);
  k_scan2<<<1, 512, 0, stream>>>(bsum, IBLK);
  k_scan3<<<IBLK, 256, 0, stream>>>(deg, bsum, offs, cur);
  // CSR build: two-pass partition (coalesced; replaces random scatter)
  k_binit<<<2, 256, 0, stream>>>(offs, pbcur);
  k_part1<<<(EE + TILE - 1) / TILE, 256, 0, stream>>>(ei, pbcur, ebuf);
  k_part2<<<NBK, 256, 0, stream>>>(ebuf, offs, cur, csr);
  // GEMM: MFMA main path + layout self-check + scalar fallback
  k_wfrag<<<8, 256, 0, stream>>>(w, wfrag);
  k_gemm_mfma<<<NN / 32, 256, 0, stream>>>(x, wfrag, hW16);
  k_check<<<16, 256, 0, stream>>>(x, w, hW16, mflag);
  k_gemm_fb<<<(NN + 15) / 16, 256, 0, stream>>>(x, w, hW16, mflag);
  k_agg<<<(NN + 3) / 4, 256, 0, stream>>>((const u32*)hW16, dinv32, offs, deg, csr,
                                          bias, hc, key, gate);
  k_minmax<<<IBLK, 256, 0, stream>>>(key, meta);
  k_shift<<<1, 1, 0, stream>>>(meta);
  k_hist<<<(NN + 255) / 256, 256, 0, stream>>>(key, meta, barr, bcnt);
  k_bscan1<<<SBLK, 256, 0, stream>>>(bcnt, bsum2);
  k_scan2<<<1, 512, 0, stream>>>(bsum2, SBLK);
  k_bscan3<<<SBLK, 256, 0, stream>>>(bcnt, bsum2, base, bcur);
  k_bscatter<<<(NN + 255) / 256, 256, 0, stream>>>(barr, bcur, blist);
  k_rank2<<<(NN + 255) / 256, 256, 0, stream>>>(key, barr, bcnt, base, blist, arank);
  // exact band repair (f64 truth via linearity)
  k_bandsel<<<(NN + 255) / 256, 256, 0, stream>>>(arank, bandNode);
  k_bscore<<<(2 * BB) / 4, 256, 0, stream>>>(bandNode, x, w, dinv64, offs, deg, csr,
                                             bias, ekey);
  k_bandrank<<<(2 * BB) / 256, 256, 0, stream>>>(ekey, brank);
  k_pos2<<<(NN + 255) / 256, 256, 0, stream>>>(arank, brank, pos);
  k_xout<<<(NN * DD + 255) / 256, 256, 0, stream>>>(hc, gate, pos, outx);
  float* oei = outx + (size_t)KK * DD;
  k_edges<<<(EE + 255) / 256, 256, 0, stream>>>(ei, pos, oei, oei + EE, oei + 2 * (size_t)EE);
}

// Round 8
// 528.758 us; speedup vs baseline: 3.7859x; 1.0550x over previous
//
#include <hip/hip_runtime.h>
#include <hip/hip_fp16.h>
#include <stdint.h>

#define NN 100000
#define EE 3200000
#define DD 128
#define KK 50000
#define NB 65536    // rank buckets (2^16)
#define SBLK 256    // NB / 256
#define BB 2048     // band half-width around rank K (band size 2*BB)
#define NBK 391     // coarse edge buckets (256 dst nodes each)
#define TILE 8192   // edges per k_part1 block
#define BMAX 12288  // max edges per coarse bucket staged in LDS (14 sigma)

using u16 = unsigned short;
using u32 = unsigned int;
using u64 = unsigned long long;

typedef _Float16 f16x8 __attribute__((ext_vector_type(8)));
typedef float f32x4 __attribute__((ext_vector_type(4)));

// f32 -> bf16(RNE) -> f32, matching the harness's bf16-quantized reference.
__device__ __forceinline__ float bq(float f) {
  u32 b = __float_as_uint(f);
  b += 0x7FFFu + ((b >> 16) & 1u);
  return __uint_as_float(b & 0xFFFF0000u);
}

// ---------------- init (replaces 4 hipMemsetAsync dispatches) ----------------
__global__ void k_init(u32* __restrict__ deg, u32* __restrict__ bcnt,
                       u64* __restrict__ meta, u32* __restrict__ mflag) {
  int i = blockIdx.x * 256 + threadIdx.x;
  for (int j = i; j < NN; j += 256 * 256) deg[j] = 0u;
  for (int j = i; j < NB; j += 256 * 256) bcnt[j] = 0u;
  if (i == 0) { meta[0] = ~0ull; meta[1] = 0ull; *mflag = 0u; }
}

// ---------------- degree histogram ----------------
__global__ void k_deg(const int* __restrict__ ei, u32* __restrict__ deg) {
  int e = blockIdx.x * blockDim.x + threadIdx.x;
  if (e < EE) atomicAdd(&deg[ei[EE + e]], 1u);
}

__global__ void k_dinv(const u32* __restrict__ deg, double* __restrict__ dinv64,
                       float* __restrict__ dinv32) {
  int i = blockIdx.x * blockDim.x + threadIdx.x;
  if (i < NN) {
    double d = 1.0 / sqrt((double)(deg[i] + 1u)); // +1 self-loop
    dinv64[i] = d;
    dinv32[i] = (float)d;
  }
}

// ---------------- CSR offsets: 3-kernel scan ----------------
#define IBLK 391

__global__ void k_scan1(const u32* __restrict__ deg, u32* __restrict__ bsum) {
  __shared__ u32 sh[256];
  int t = threadIdx.x; int i = blockIdx.x * 256 + t;
  u32 v = (i < NN) ? deg[i] : 0u;
  sh[t] = v; __syncthreads();
  for (int s = 128; s > 0; s >>= 1) { if (t < s) sh[t] += sh[t + s]; __syncthreads(); }
  if (t == 0) bsum[blockIdx.x] = sh[0];
}

__global__ void k_scan2(u32* __restrict__ bsum, int nb) { // 1 block, 512 thr, nb<=512
  __shared__ u32 buf[2][512];
  int t = threadIdx.x;
  u32 v = (t < nb) ? bsum[t] : 0u;
  int a = 0; buf[0][t] = v; __syncthreads();
  for (int s = 1; s < 512; s <<= 1) {
    buf[1 - a][t] = buf[a][t] + ((t >= s) ? buf[a][t - s] : 0u);
    a = 1 - a; __syncthreads();
  }
  if (t < nb) bsum[t] = buf[a][t] - v; // exclusive
}

__global__ void k_scan3(const u32* __restrict__ deg, const u32* __restrict__ bsum,
                        u32* __restrict__ offs, u32* __restrict__ cur) {
  __shared__ u32 buf[2][256];
  int t = threadIdx.x; int i = blockIdx.x * 256 + t;
  u32 v = (i < NN) ? deg[i] : 0u;
  int a = 0; buf[0][t] = v; __syncthreads();
  for (int s = 1; s < 256; s <<= 1) {
    buf[1 - a][t] = buf[a][t] + ((t >= s) ? buf[a][t - s] : 0u);
    a = 1 - a; __syncthreads();
  }
  if (i < NN) {
    u32 exc = buf[a][t] - v + bsum[blockIdx.x];
    offs[i] = exc; cur[i] = exc;
  }
}

// ---------------- CSR build: two-pass LDS-staged partition ----------------
__global__ void k_binit(const u32* __restrict__ offs, u32* __restrict__ bcur) {
  int b = blockIdx.x * 256 + threadIdx.x;
  if (b < NBK) bcur[b] = offs[b * 256];
}

// pass 1: partition edges into 391 coarse buckets (coalesced run flushes)
__global__ void k_part1(const int* __restrict__ ei, u32* __restrict__ bcur,
                        u32* __restrict__ ebuf) {
  __shared__ u32 cnt[NBK];
  __shared__ u32 lpos[NBK];
  __shared__ u32 gbase[NBK];
  __shared__ u32 sbuf[TILE];  // 32 KiB packed entries, bucket-sorted
  __shared__ u16 sbid[TILE];  // 16 KiB bucket id per slot
  int t = threadIdx.x;
  int e0 = blockIdx.x * TILE;
  int vcnt = EE - e0; if (vcnt > TILE) vcnt = TILE;
  for (int i = t; i < NBK; i += 256) cnt[i] = 0;
  __syncthreads();
  for (int i = t; i < vcnt; i += 256) {
    int d = ei[EE + e0 + i];
    atomicAdd(&cnt[d >> 8], 1u);
  }
  __syncthreads();
  // exclusive scan cnt -> lpos (wave 0, shfl segments of 64)
  if (t < 64) {
    u32 carry = 0;
    for (int c = 0; c < 7; ++c) {
      int idx = c * 64 + t;
      u32 v = (idx < NBK) ? cnt[idx] : 0u;
      u32 x = v;
      #pragma unroll
      for (int s = 1; s < 64; s <<= 1) {
        u32 y = __shfl_up(x, s);
        if (t >= s) x += y;
      }
      if (idx < NBK) lpos[idx] = x - v + carry;
      carry += __shfl(x, 63);
    }
  }
  __syncthreads();
  for (int i = t; i < NBK; i += 256)
    gbase[i] = cnt[i] ? atomicAdd(&bcur[i], cnt[i]) : 0u;
  // local scatter (bucket-sorted within the tile)
  for (int i = t; i < vcnt; i += 256) {
    int d = ei[EE + e0 + i];
    int s = ei[e0 + i];
    u32 b = (u32)d >> 8;
    u32 p = atomicAdd(&lpos[b], 1u);
    sbuf[p] = ((u32)(d & 255) << 17) | (u32)s;
    sbid[p] = (u16)b;
  }
  __syncthreads();
  // coalesced run flush
  for (int i = t; i < vcnt; i += 256) {
    u32 b = sbid[i];
    u32 lstart = lpos[b] - cnt[b];
    ebuf[gbase[b] + ((u32)i - lstart)] = sbuf[i];
  }
}

// pass 2: within each bucket, exact csr positions via LDS cursors, coalesced out
__global__ void k_part2(const u32* __restrict__ ebuf, const u32* __restrict__ offs,
                        u32* __restrict__ cur, int* __restrict__ csr) {
  __shared__ u32 ncur[256];
  __shared__ u32 scsr[BMAX]; // 48 KiB
  int b = blockIdx.x; int t = threadIdx.x;
  int nbase = b * 256;
  u32 gstart = offs[nbase];
  u32 gend = (nbase + 256 < NN) ? offs[nbase + 256] : (u32)EE;
  u32 cnt = gend - gstart;
  if (nbase + t < NN) ncur[t] = offs[nbase + t] - gstart;
  __syncthreads();
  if (cnt <= (u32)BMAX) {
    for (u32 i = t; i < cnt; i += 256) {
      u32 en = ebuf[gstart + i];
      u32 p = atomicAdd(&ncur[en >> 17], 1u);
      scsr[p] = en & 0x1FFFFu;
    }
    __syncthreads();
    for (u32 i = t; i < cnt; i += 256) csr[gstart + i] = (int)scsr[i];
  } else { // statistically unreachable fallback: direct global scatter
    for (u32 i = t; i < cnt; i += 256) {
      u32 en = ebuf[gstart + i];
      u32 p = atomicAdd(&cur[nbase + (en >> 17)], 1u);
      csr[p] = (int)(en & 0x1FFFFu);
    }
  }
}

// ------- W -> per-lane f16 MFMA fragments -------
__global__ void k_wfrag(const float* __restrict__ w, f16x8* __restrict__ wfrag) {
  int idx = blockIdx.x * 256 + threadIdx.x; // 2048 total
  int lane = idx & 63;
  int ctt = (idx >> 6) & 7;
  int kstep = idx >> 9;
  int c = ctt * 16 + (lane & 15);
  int kbase = (lane >> 4) * 8 + kstep * 32;
  f16x8 v;
  #pragma unroll
  for (int j = 0; j < 8; ++j) v[j] = (_Float16)w[(kbase + j) * DD + c];
  wfrag[idx] = v;
}

// ------- h = x @ W via MFMA 16x16x32 f16 (f32 accumulate, emit fp16) -------
__global__ void __launch_bounds__(256) k_gemm_mfma(const float* __restrict__ x,
                                                   const f16x8* __restrict__ wfrag,
                                                   u16* __restrict__ hW16) {
  int wid = threadIdx.x >> 6, lane = threadIdx.x & 63;
  int rowbase = blockIdx.x * 32 + (wid & 1) * 16;
  int colgrp = wid >> 1; // 0..1, 64 cols each
  int row = rowbase + (lane & 15);
  int klane = (lane >> 4) * 8;

  f32x4 acc[4] = {{0,0,0,0},{0,0,0,0},{0,0,0,0},{0,0,0,0}};
  const float* xr = x + (size_t)row * DD;
  #pragma unroll
  for (int kstep = 0; kstep < 4; ++kstep) {
    const float4* xp = (const float4*)(xr + klane + kstep * 32);
    float4 v0 = xp[0], v1 = xp[1];
    f16x8 a;
    a[0] = (_Float16)v0.x; a[1] = (_Float16)v0.y;
    a[2] = (_Float16)v0.z; a[3] = (_Float16)v0.w;
    a[4] = (_Float16)v1.x; a[5] = (_Float16)v1.y;
    a[6] = (_Float16)v1.z; a[7] = (_Float16)v1.w;
    #pragma unroll
    for (int ct = 0; ct < 4; ++ct) {
      f16x8 b = wfrag[(kstep * 8 + colgrp * 4 + ct) * 64 + lane];
      acc[ct] = __builtin_amdgcn_mfma_f32_16x16x32_f16(a, b, acc[ct], 0, 0, 0);
    }
  }
  // D layout: col = lane&15, row = (lane>>4)*4 + reg   [m89-verified]
  #pragma unroll
  for (int ct = 0; ct < 4; ++ct) {
    int col = colgrp * 64 + ct * 16 + (lane & 15);
    #pragma unroll
    for (int reg = 0; reg < 4; ++reg) {
      int r = rowbase + (lane >> 4) * 4 + reg;
      hW16[(size_t)r * DD + col] = __half_as_ushort(__float2half(acc[ct][reg]));
    }
  }
}

// ------- verify MFMA fragment layout on block-tile 0; flag on mismatch -------
__global__ void k_check(const float* __restrict__ x, const float* __restrict__ w,
                        const u16* __restrict__ hW16, u32* __restrict__ flag) {
  int idx = blockIdx.x * 256 + threadIdx.x; // 4096 = 32 rows x 128 cols
  int r = idx >> 7, c = idx & 127;
  const float4* xr = (const float4*)(x + (size_t)r * DD);
  float acc = 0.0f;
  #pragma unroll 8
  for (int k4 = 0; k4 < 32; ++k4) {
    float4 xv = xr[k4];
    int kb = k4 * 4;
    acc += xv.x * w[kb * DD + c] + xv.y * w[(kb + 1) * DD + c]
         + xv.z * w[(kb + 2) * DD + c] + xv.w * w[(kb + 3) * DD + c];
  }
  float got = __half2float(__ushort_as_half(hW16[r * DD + c]));
  if (fabsf(got - acc) > 0.02f) atomicOr(flag, 1u);
}

// ------- scalar fallback GEMM (runs only if MFMA layout check failed) -------
__global__ void k_gemm_fb(const float* __restrict__ x, const float* __restrict__ w,
                          u16* __restrict__ hW16, const u32* __restrict__ flag) {
  if (*flag == 0u) return;
  __shared__ float Wl[DD * DD]; // 64 KiB
  int t = threadIdx.x;
  for (int i = t; i < DD * DD; i += 256) Wl[i] = w[i];
  __syncthreads();
  int base = blockIdx.x * 16;
  int c = t & 127, rh = t >> 7;
  for (int it = 0; it < 8; ++it) {
    int r = base + it * 2 + rh;
    if (r < NN) {
      const float4* xr = (const float4*)(x + (size_t)r * DD);
      float acc = 0.0f;
      #pragma unroll 4
      for (int k4 = 0; k4 < 32; ++k4) {
        float4 xv = xr[k4];
        int kb = k4 * 4;
        acc += xv.x * Wl[kb * DD + c];
        acc += xv.y * Wl[(kb + 1) * DD + c];
        acc += xv.z * Wl[(kb + 2) * DD + c];
        acc += xv.w * Wl[(kb + 3) * DD + c];
      }
      hW16[(size_t)r * DD + c] = __half_as_ushort(__float2half(acc));
    }
  }
}

// ---- gather-aggregate: 2 nodes/wave (32 lanes, 4 dims/lane via uint2) ----
__global__ void k_agg(const u32* __restrict__ hw, const float* __restrict__ dinv32,
                      const u32* __restrict__ offs, const u32* __restrict__ deg,
                      const int* __restrict__ csr, const float* __restrict__ bias,
                      float* __restrict__ hc, u64* __restrict__ key,
                      float* __restrict__ gate) {
  int wid = threadIdx.x >> 6;
  int lane = threadIdx.x & 63;
  int half = lane >> 5;    // which of the wave's 2 nodes
  int l5 = lane & 31;      // handles dims 4*l5 .. 4*l5+3
  int node = blockIdx.x * 8 + wid * 2 + half;
  if (node >= NN) return;
  const uint2* hwp = (const uint2*)hw;
  float di = dinv32[node];
  float a0 = 0.f, a1 = 0.f, a2 = 0.f, a3 = 0.f;
  u32 o = offs[node], cnt = deg[node];
  u32 k = 0;
  for (; k + 4 <= cnt; k += 4) {
    int s0 = csr[o + k], s1 = csr[o + k + 1], s2 = csr[o + k + 2], s3 = csr[o + k + 3];
    float n0 = dinv32[s0] * di, n1 = dinv32[s1] * di;
    float n2 = dinv32[s2] * di, n3 = dinv32[s3] * di;
    uint2 w0 = hwp[(size_t)s0 * 32 + l5];
    uint2 w1 = hwp[(size_t)s1 * 32 + l5];
    uint2 w2 = hwp[(size_t)s2 * 32 + l5];
    uint2 w3 = hwp[(size_t)s3 * 32 + l5];
    float2 p0 = __half22float2(*(__half2*)&w0.x), q0 = __half22float2(*(__half2*)&w0.y);
    float2 p1 = __half22float2(*(__half2*)&w1.x), q1 = __half22float2(*(__half2*)&w1.y);
    float2 p2 = __half22float2(*(__half2*)&w2.x), q2 = __half22float2(*(__half2*)&w2.y);
    float2 p3 = __half22float2(*(__half2*)&w3.x), q3 = __half22float2(*(__half2*)&w3.y);
    a0 += p0.x * n0 + p1.x * n1 + p2.x * n2 + p3.x * n3;
    a1 += p0.y * n0 + p1.y * n1 + p2.y * n2 + p3.y * n3;
    a2 += q0.x * n0 + q1.x * n1 + q2.x * n2 + q3.x * n3;
    a3 += q0.y * n0 + q1.y * n1 + q2.y * n2 + q3.y * n3;
  }
  for (; k < cnt; ++k) {
    int s = csr[o + k];
    float nrm = dinv32[s] * di;
    uint2 wb = hwp[(size_t)s * 32 + l5];
    float2 p = __half22float2(*(__half2*)&wb.x), q = __half22float2(*(__half2*)&wb.y);
    a0 += p.x * nrm; a1 += p.y * nrm; a2 += q.x * nrm; a3 += q.y * nrm;
  }
  float di2 = di * di;
  uint2 wb = hwp[(size_t)node * 32 + l5];
  float2 p = __half22float2(*(__half2*)&wb.x), q = __half22float2(*(__half2*)&wb.y);
  float4 bv = ((const float4*)bias)[l5];
  a0 += p.x * di2 + bv.x;
  a1 += p.y * di2 + bv.y;
  a2 += q.x * di2 + bv.z;
  a3 += q.y * di2 + bv.w;
  float4 out = make_float4(a0, a1, a2, a3);
  ((float4*)hc)[(size_t)node * 32 + l5] = out;
  float ss = a0 * a0 + a1 * a1 + a2 * a2 + a3 * a3;
  #pragma unroll
  for (int off = 16; off > 0; off >>= 1) ss += __shfl_xor(ss, off);
  if (l5 == 0) {
    // approx key: f32 ss bits (monotone in score, ss >= 0);
    // low 17 bits = (0x1FFFF - node) => lower index wins ties
    u32 sb = __float_as_uint(ss);
    key[node] = ((u64)sb << 17) | (u64)(0x1FFFF - node);
    gate[node] = tanhf(sqrtf(ss + 1e-12f));
  }
}

// ---------------- exact bucket-rank (approx keys -> full rank) ----------------
__global__ void k_minmax(const u64* __restrict__ key, u64* __restrict__ meta) {
  __shared__ u64 smn[256], smx[256];
  int t = threadIdx.x; int i = blockIdx.x * 256 + t;
  u64 v = (i < NN) ? key[i] : key[0];
  smn[t] = v; smx[t] = v; __syncthreads();
  for (int s = 128; s > 0; s >>= 1) {
    if (t < s) {
      if (smn[t + s] < smn[t]) smn[t] = smn[t + s];
      if (smx[t + s] > smx[t]) smx[t] = smx[t + s];
    }
    __syncthreads();
  }
  if (t == 0) { atomicMin(&meta[0], smn[0]); atomicMax(&meta[1], smx[0]); }
}

__device__ __forceinline__ u32 bshift(u64 kmin, u64 kmax) {
  u64 range = kmax - kmin;
  int bits = 64 - __clzll(range | 1ull);
  return (u32)(bits > 16 ? bits - 16 : 0); // 2^16 buckets
}

__global__ void k_hist(const u64* __restrict__ key, const u64* __restrict__ meta,
                       u32* __restrict__ barr, u32* __restrict__ bcnt) {
  int i = blockIdx.x * blockDim.x + threadIdx.x;
  if (i >= NN) return;
  u64 kmin = meta[0];
  u32 sh = bshift(kmin, meta[1]);
  u32 b = (u32)((key[i] - kmin) >> sh);
  barr[i] = b;
  atomicAdd(&bcnt[b], 1u);
}

__global__ void k_bscan1(const u32* __restrict__ bcnt, u32* __restrict__ bsum2) {
  __shared__ u32 sh[256];
  int t = threadIdx.x; int r = blockIdx.x * 256 + t;
  u32 v = bcnt[NB - 1 - r];
  sh[t] = v; __syncthreads();
  for (int s = 128; s > 0; s >>= 1) { if (t < s) sh[t] += sh[t + s]; __syncthreads(); }
  if (t == 0) bsum2[blockIdx.x] = sh[0];
}

__global__ void k_bscan3(const u32* __restrict__ bcnt, const u32* __restrict__ bsum2,
                         u32* __restrict__ base, u32* __restrict__ bcur) {
  __shared__ u32 buf[2][256];
  int t = threadIdx.x; int r = blockIdx.x * 256 + t;
  int b = NB - 1 - r;
  u32 v = bcnt[b];
  int a = 0; buf[0][t] = v; __syncthreads();
  for (int s = 1; s < 256; s <<= 1) {
    buf[1 - a][t] = buf[a][t] + ((t >= s) ? buf[a][t - s] : 0u);
    a = 1 - a; __syncthreads();
  }
  u32 bs = buf[a][t] - v + bsum2[blockIdx.x]; // suffix-exclusive
  base[b] = bs;
  bcur[b] = NN - bs - v;
}

__global__ void k_bscatter(const u32* __restrict__ barr, u32* __restrict__ bcur,
                           u32* __restrict__ blist) {
  int i = blockIdx.x * blockDim.x + threadIdx.x;
  if (i >= NN) return;
  u32 p = atomicAdd(&bcur[barr[i]], 1u);
  blist[p] = (u32)i;
}

// rank + in-band selection fused
__global__ void k_rank2(const u64* __restrict__ key, const u32* __restrict__ barr,
                        const u32* __restrict__ bcnt, const u32* __restrict__ base,
                        const u32* __restrict__ blist, int* __restrict__ arank,
                        u32* __restrict__ bandNode) {
  int i = blockIdx.x * blockDim.x + threadIdx.x;
  if (i >= NN) return;
  u32 b = barr[i];
  u64 ki = key[i];
  u32 bs = base[b], cnt = bcnt[b];
  u32 off = NN - bs - cnt;
  u32 gt = 0;
  for (u32 j = 0; j < cnt; ++j) gt += (key[blist[off + j]] > ki) ? 1u : 0u;
  int r = (int)(bs + gt);
  arank[i] = r; // full approx rank (a permutation of 0..NN-1)
  int rb = r - (KK - BB);
  if (rb >= 0 && rb < 2 * BB) bandNode[rb] = (u32)i;
}

// ---------------- exact band repair ----------------
// exact f64 rescore via linearity: a = (sum_s wgt_s * x_s) @ W + bias
__global__ void k_bscore(const u32* __restrict__ bandNode,
                         const float* __restrict__ x, const float* __restrict__ w,
                         const double* __restrict__ dinv64,
                         const u32* __restrict__ offs, const u32* __restrict__ deg,
                         const int* __restrict__ csr, const float* __restrict__ bias,
                         u64* __restrict__ ekey) {
  __shared__ double zsh[4][DD]; // 4 KiB
  int wid = threadIdx.x >> 6;
  int lane = threadIdx.x & 63;
  int slot = blockIdx.x * 4 + wid;
  int node = (int)bandNode[slot];
  double di = dinv64[node];
  double z0 = 0.0, z1 = 0.0;
  u32 o = offs[node], cnt = deg[node];
  for (u32 k = 0; k <= cnt; ++k) { // last iter = self row
    int s = (k < cnt) ? csr[o + k] : node;
    double wgt = (k < cnt) ? (dinv64[s] * di) : (di * di);
    float2 xv = ((const float2*)x)[(size_t)s * 64 + lane];
    z0 += (double)xv.x * wgt;
    z1 += (double)xv.y * wgt;
  }
  zsh[wid][2 * lane] = z0;
  zsh[wid][2 * lane + 1] = z1;
  __syncthreads();
  float2 bv = ((const float2*)bias)[lane];
  double a0 = (double)bv.x, a1 = (double)bv.y;
  for (int kk = 0; kk < DD; ++kk) {
    double zk = zsh[wid][kk];
    float2 wv = ((const float2*)w)[kk * 64 + lane];
    a0 += zk * (double)wv.x;
    a1 += zk * (double)wv.y;
  }
  double ss = a0 * a0 + a1 * a1;
  #pragma unroll
  for (int off = 32; off > 0; off >>= 1) ss += __shfl_xor(ss, off);
  if (lane == 0) {
    double sc = sqrt(ss + 1e-12);
    u64 bits = (u64)__double_as_longlong(sc);
    ekey[slot] = (bits & ~0x1FFFFull) | (u64)(0x1FFFF - node);
  }
}

__global__ void k_bandrank(const u64* __restrict__ ekey, u32* __restrict__ brank) {
  __shared__ u64 sk[2 * BB]; // 32 KiB
  int t = threadIdx.x;
  for (int j = t; j < 2 * BB; j += 256) sk[j] = ekey[j];
  __syncthreads();
  int idx = blockIdx.x * 256 + t;
  u64 kk = sk[idx];
  u32 c = 0;
  for (int j = 0; j < 2 * BB; ++j) c += (sk[j] > kk) ? 1u : 0u;
  brank[idx] = c;
}

__global__ void k_pos2(const int* __restrict__ arank, const u32* __restrict__ brank,
                       int* __restrict__ pos) {
  int i = blockIdx.x * blockDim.x + threadIdx.x;
  if (i >= NN) return;
  int r = arank[i];
  int p;
  if (r < KK - BB) p = r;                       // surely kept
  else if (r < KK + BB) {                       // band: exact order decides
    u32 br = brank[r - (KK - BB)];
    p = (br < BB) ? (KK - BB + (int)br) : -1;
  } else p = -1;                                // surely dropped
  pos[i] = p;
}

// ---------------- outputs (f32, bf16-RNE-quantized) ----------------
__global__ void k_xout(const float* __restrict__ hc, const float* __restrict__ gate,
                       const int* __restrict__ pos, float* __restrict__ outx) {
  int id = blockIdx.x * blockDim.x + threadIdx.x;
  if (id >= NN * DD) return;
  int i = id >> 7, d = id & 127;
  int p = pos[i];
  if (p < 0) return;
  float v = hc[(size_t)i * DD + d] * gate[i];
  outx[(size_t)p * DD + d] = bq(v);
}

__global__ void k_edges(const int* __restrict__ ei, const int* __restrict__ pos,
                        float* __restrict__ osrc, float* __restrict__ odst,
                        float* __restrict__ omask) {
  int e = blockIdx.x * blockDim.x + threadIdx.x;
  if (e >= EE) return;
  int ns = pos[ei[e]];
  int nd = pos[ei[EE + e]];
  bool m = (ns >= 0) && (nd >= 0);
  osrc[e] = m ? bq((float)ns) : -1.0f;
  odst[e] = m ? bq((float)nd) : -1.0f;
  omask[e] = m ? 1.0f : 0.0f;
}

// ---------------- driver ----------------
extern "C" void kernel_launch(void* const* d_in, const int* in_sizes, int n_in,
                              void* d_out, int out_size, void* d_ws, size_t ws_size,
                              hipStream_t stream) {
  const float* x    = (const float*)d_in[0];
  const int*   ei   = (const int*)d_in[1];
  const float* w    = (const float*)d_in[2];
  const float* bias = (const float*)d_in[3];
  float* outx = (float*)d_out;
  char* ws = (char*)d_ws;

  size_t off = 0;
  auto alloc = [&](size_t b) -> void* {
    void* p = ws + off; off += (b + 255) & ~(size_t)255; return p;
  };
  u16*    hW16   = (u16*)alloc((size_t)NN * DD * 2);
  float*  hc     = (float*)alloc((size_t)NN * DD * 4);
  double* dinv64 = (double*)alloc((size_t)NN * 8);
  float*  dinv32 = (float*)alloc((size_t)NN * 4);
  float*  gate   = (float*)alloc((size_t)NN * 4);
  u64*    key    = (u64*)alloc((size_t)NN * 8);
  u32*    deg    = (u32*)alloc((size_t)NN * 4);
  u32*    offs   = (u32*)alloc((size_t)NN * 4);
  u32*    cur    = (u32*)alloc((size_t)NN * 4);
  int*    csr    = (int*)alloc((size_t)EE * 4);
  u32*    ebuf   = (u32*)alloc((size_t)EE * 4);
  u32*    pbcur  = (u32*)alloc((size_t)NBK * 4);
  int*    arank  = (int*)alloc((size_t)NN * 4);
  int*    pos    = (int*)alloc((size_t)NN * 4);
  u32*    bsum   = (u32*)alloc(512 * 4);
  u64*    meta   = (u64*)alloc(4 * 8);
  u32*    bcnt   = (u32*)alloc((size_t)NB * 4);
  u32*    base   = (u32*)alloc((size_t)NB * 4);
  u32*    bcur   = (u32*)alloc((size_t)NB * 4);
  u32*    bsum2  = (u32*)alloc(SBLK * 4);
  u32*    barr   = (u32*)alloc((size_t)NN * 4);
  u32*    blist  = (u32*)alloc((size_t)NN * 4);
  u32*    bandNode = (u32*)alloc((size_t)2 * BB * 4);
  u64*    ekey     = (u64*)alloc((size_t)2 * BB * 8);
  u32*    brank    = (u32*)alloc((size_t)2 * BB * 4);
  f16x8*  wfrag    = (f16x8*)alloc((size_t)2048 * 16);
  u32*    mflag    = (u32*)alloc(256);

  k_init<<<256, 256, 0, stream>>>(deg, bcnt, meta, mflag);
  k_deg<<<(EE + 255) / 256, 256, 0, stream>>>(ei, deg);
  k_dinv<<<(NN + 255) / 256, 256, 0, stream>>>(deg, dinv64, dinv32);
  k_scan1<<<IBLK, 256, 0, stream>>>(deg, bsum);
  k_scan2<<<1, 512, 0, stream>>>(bsum, IBLK);
  k_scan3<<<IBLK, 256, 0, stream>>>(deg, bsum, offs, cur);
  // CSR build: two-pass partition (coalesced)
  k_binit<<<2, 256, 0, stream>>>(offs, pbcur);
  k_part1<<<(EE + TILE - 1) / TILE, 256, 0, stream>>>(ei, pbcur, ebuf);
  k_part2<<<NBK, 256, 0, stream>>>(ebuf, offs, cur, csr);
  // GEMM: MFMA main path + layout self-check + scalar fallback
  k_wfrag<<<8, 256, 0, stream>>>(w, wfrag);
  k_gemm_mfma<<<NN / 32, 256, 0, stream>>>(x, wfrag, hW16);
  k_check<<<16, 256, 0, stream>>>(x, w, hW16, mflag);
  k_gemm_fb<<<(NN + 15) / 16, 256, 0, stream>>>(x, w, hW16, mflag);
  k_agg<<<(NN + 7) / 8, 256, 0, stream>>>((const u32*)hW16, dinv32, offs, deg, csr,
                                          bias, hc, key, gate);
  k_minmax<<<IBLK, 256, 0, stream>>>(key, meta);
  k_hist<<<(NN + 255) / 256, 256, 0, stream>>>(key, meta, barr, bcnt);
  k_bscan1<<<SBLK, 256, 0, stream>>>(bcnt, bsum2);
  k_scan2<<<1, 512, 0, stream>>>(bsum2, SBLK);
  k_bscan3<<<SBLK, 256, 0, stream>>>(bcnt, bsum2, base, bcur);
  k_bscatter<<<(NN + 255) / 256, 256, 0, stream>>>(barr, bcur, blist);
  k_rank2<<<(NN + 255) / 256, 256, 0, stream>>>(key, barr, bcnt, base, blist, arank,
                                                bandNode);
  // exact band repair (f64 truth via linearity)
  k_bscore<<<(2 * BB) / 4, 256, 0, stream>>>(bandNode, x, w, dinv64, offs, deg, csr,
                                             bias, ekey);
  k_bandrank<<<(2 * BB) / 256, 256, 0, stream>>>(ekey, brank);
  k_pos2<<<(NN + 255) / 256, 256, 0, stream>>>(arank, brank, pos);
  k_xout<<<(NN * DD + 255) / 256, 256, 0, stream>>>(hc, gate, pos, outx);
  float* oei = outx + (size_t)KK * DD;
  k_edges<<<(EE + 255) / 256, 256, 0, stream>>>(ei, pos, oei, oei + EE, oei + 2 * (size_t)EE);
}

// Round 10
// 407.990 us; speedup vs baseline: 4.9066x; 1.2960x over previous
//
#include <hip/hip_runtime.h>
#include <hip/hip_fp16.h>
#include <stdint.h>

#define NN 100000
#define EE 3200000
#define DD 128
#define KK 50000
#define NB 65536    // rank buckets (2^16)
#define SBLK 256    // NB / 256
#define BB 2048     // band half-width around rank K (band size 2*BB)
#define NBK 391     // coarse edge buckets (256 dst nodes each)
#define TILE 8192   // edges per partition block
#define BMAX 12288  // max edges per coarse bucket staged in LDS (14 sigma)
#define NBLK 391    // ceil(NN / 256)

using u16 = unsigned short;
using u32 = unsigned int;
using u64 = unsigned long long;

typedef _Float16 f16x8 __attribute__((ext_vector_type(8)));
typedef float f32x4 __attribute__((ext_vector_type(4)));

// f32 -> bf16(RNE) -> f32, matching the harness's bf16-quantized reference.
__device__ __forceinline__ float bq(float f) {
  u32 b = __float_as_uint(f);
  b += 0x7FFFu + ((b >> 16) & 1u);
  return __uint_as_float(b & 0xFFFF0000u);
}

// ---------------- init ----------------
__global__ void k_init(u32* __restrict__ chist, u32* __restrict__ bcnt,
                       u64* __restrict__ meta, u32* __restrict__ mflag) {
  int i = blockIdx.x * 256 + threadIdx.x;
  for (int j = i; j < NB; j += 256 * 256) bcnt[j] = 0u;
  if (i < NBK) chist[i] = 0u;
  if (i == 0) { meta[0] = ~0ull; meta[1] = 0ull; *mflag = 0u; }
}

// ---------------- coarse dst histogram (LDS-privatized) ----------------
__global__ void k_chist(const int* __restrict__ ei, u32* __restrict__ chist) {
  __shared__ u32 cnt[NBK];
  int t = threadIdx.x;
  int e0 = blockIdx.x * TILE;
  int vcnt = EE - e0; if (vcnt > TILE) vcnt = TILE;
  for (int i = t; i < NBK; i += 256) cnt[i] = 0;
  __syncthreads();
  for (int i = t; i < vcnt; i += 256)
    atomicAdd(&cnt[(u32)ei[EE + e0 + i] >> 8], 1u);
  __syncthreads();
  for (int i = t; i < NBK; i += 256)
    if (cnt[i]) atomicAdd(&chist[i], cnt[i]);
}

// scan coarse histogram -> bucket bases (cbase) + partition cursors (pbcur)
__global__ void k_cscan(const u32* __restrict__ chist, u32* __restrict__ cbase,
                        u32* __restrict__ pbcur) {
  __shared__ u32 buf[2][512];
  int t = threadIdx.x;
  u32 v = (t < NBK) ? chist[t] : 0u;
  int a = 0; buf[0][t] = v; __syncthreads();
  for (int s = 1; s < 512; s <<= 1) {
    buf[1 - a][t] = buf[a][t] + ((t >= s) ? buf[a][t - s] : 0u);
    a = 1 - a; __syncthreads();
  }
  if (t < NBK) { u32 e = buf[a][t] - v; cbase[t] = e; pbcur[t] = e; }
}

// pass 1: partition edges into 391 coarse buckets (coalesced run flushes)
__global__ void k_part1(const int* __restrict__ ei, u32* __restrict__ bcur,
                        u32* __restrict__ ebuf) {
  __shared__ u32 cnt[NBK];
  __shared__ u32 lpos[NBK];
  __shared__ u32 gbase[NBK];
  __shared__ u32 sbuf[TILE];  // 32 KiB packed entries, bucket-sorted
  __shared__ u16 sbid[TILE];  // 16 KiB bucket id per slot
  int t = threadIdx.x;
  int e0 = blockIdx.x * TILE;
  int vcnt = EE - e0; if (vcnt > TILE) vcnt = TILE;
  for (int i = t; i < NBK; i += 256) cnt[i] = 0;
  __syncthreads();
  for (int i = t; i < vcnt; i += 256) {
    int d = ei[EE + e0 + i];
    atomicAdd(&cnt[d >> 8], 1u);
  }
  __syncthreads();
  // exclusive scan cnt -> lpos (wave 0, shfl segments of 64)
  if (t < 64) {
    u32 carry = 0;
    for (int c = 0; c < 7; ++c) {
      int idx = c * 64 + t;
      u32 v = (idx < NBK) ? cnt[idx] : 0u;
      u32 x = v;
      #pragma unroll
      for (int s = 1; s < 64; s <<= 1) {
        u32 y = __shfl_up(x, s);
        if (t >= s) x += y;
      }
      if (idx < NBK) lpos[idx] = x - v + carry;
      carry += __shfl(x, 63);
    }
  }
  __syncthreads();
  for (int i = t; i < NBK; i += 256)
    gbase[i] = cnt[i] ? atomicAdd(&bcur[i], cnt[i]) : 0u;
  // local scatter (bucket-sorted within the tile)
  for (int i = t; i < vcnt; i += 256) {
    int d = ei[EE + e0 + i];
    int s = ei[e0 + i];
    u32 b = (u32)d >> 8;
    u32 p = atomicAdd(&lpos[b], 1u);
    sbuf[p] = ((u32)(d & 255) << 17) | (u32)s;
    sbid[p] = (u16)b;
  }
  __syncthreads();
  // coalesced run flush
  for (int i = t; i < vcnt; i += 256) {
    u32 b = sbid[i];
    u32 lstart = lpos[b] - cnt[b];
    ebuf[gbase[b] + ((u32)i - lstart)] = sbuf[i];
  }
}

// pass 2: fine histogram + scan (deg/offs/dinv) + exact csr, all in LDS
__global__ void k_part2(const u32* __restrict__ ebuf, const u32* __restrict__ cbase,
                        u32* __restrict__ deg, u32* __restrict__ offs,
                        double* __restrict__ dinv64, float* __restrict__ dinv32,
                        int* __restrict__ csr) {
  __shared__ u32 fcnt[256];
  __shared__ u32 buf[2][256];
  __shared__ u32 ncur[256];
  __shared__ u32 scsr[BMAX]; // 48 KiB
  int b = blockIdx.x; int t = threadIdx.x;
  int nbase = b * 256;
  u32 gstart = cbase[b];
  u32 gend = (b + 1 < NBK) ? cbase[b + 1] : (u32)EE;
  u32 cnt = gend - gstart;
  fcnt[t] = 0u;
  __syncthreads();
  for (u32 i = t; i < cnt; i += 256)
    atomicAdd(&fcnt[ebuf[gstart + i] >> 17], 1u);
  __syncthreads();
  // exclusive scan of fcnt
  u32 v = fcnt[t];
  int a = 0; buf[0][t] = v; __syncthreads();
  for (int s = 1; s < 256; s <<= 1) {
    buf[1 - a][t] = buf[a][t] + ((t >= s) ? buf[a][t - s] : 0u);
    a = 1 - a; __syncthreads();
  }
  u32 floc = buf[a][t] - v;
  int node = nbase + t;
  if (node < NN) {
    deg[node] = v;
    offs[node] = gstart + floc;
    double d = 1.0 / sqrt((double)(v + 1u)); // +1 self-loop
    dinv64[node] = d;
    dinv32[node] = (float)d;
  }
  ncur[t] = floc;
  __syncthreads();
  if (cnt <= (u32)BMAX) {
    for (u32 i = t; i < cnt; i += 256) {
      u32 en = ebuf[gstart + i];
      u32 p = atomicAdd(&ncur[en >> 17], 1u);
      scsr[p] = en & 0x1FFFFu;
    }
    __syncthreads();
    for (u32 i = t; i < cnt; i += 256) csr[gstart + i] = (int)scsr[i];
  } else { // statistically unreachable fallback: direct global scatter
    for (u32 i = t; i < cnt; i += 256) {
      u32 en = ebuf[gstart + i];
      u32 p = atomicAdd(&ncur[en >> 17], 1u);
      csr[gstart + p] = (int)(en & 0x1FFFFu);
    }
  }
}

// ------- W -> per-lane f16 MFMA fragments -------
__global__ void k_wfrag(const float* __restrict__ w, f16x8* __restrict__ wfrag) {
  int idx = blockIdx.x * 256 + threadIdx.x; // 2048 total
  int lane = idx & 63;
  int ctt = (idx >> 6) & 7;
  int kstep = idx >> 9;
  int c = ctt * 16 + (lane & 15);
  int kbase = (lane >> 4) * 8 + kstep * 32;
  f16x8 v;
  #pragma unroll
  for (int j = 0; j < 8; ++j) v[j] = (_Float16)w[(kbase + j) * DD + c];
  wfrag[idx] = v;
}

// ------- h = x @ W via MFMA 16x16x32 f16 (f32 accumulate, emit fp16) -------
__global__ void __launch_bounds__(256) k_gemm_mfma(const float* __restrict__ x,
                                                   const f16x8* __restrict__ wfrag,
                                                   u16* __restrict__ hW16) {
  int wid = threadIdx.x >> 6, lane = threadIdx.x & 63;
  int rowbase = blockIdx.x * 32 + (wid & 1) * 16;
  int colgrp = wid >> 1; // 0..1, 64 cols each
  int row = rowbase + (lane & 15);
  int klane = (lane >> 4) * 8;

  f32x4 acc[4] = {{0,0,0,0},{0,0,0,0},{0,0,0,0},{0,0,0,0}};
  const float* xr = x + (size_t)row * DD;
  #pragma unroll
  for (int kstep = 0; kstep < 4; ++kstep) {
    const float4* xp = (const float4*)(xr + klane + kstep * 32);
    float4 v0 = xp[0], v1 = xp[1];
    f16x8 a;
    a[0] = (_Float16)v0.x; a[1] = (_Float16)v0.y;
    a[2] = (_Float16)v0.z; a[3] = (_Float16)v0.w;
    a[4] = (_Float16)v1.x; a[5] = (_Float16)v1.y;
    a[6] = (_Float16)v1.z; a[7] = (_Float16)v1.w;
    #pragma unroll
    for (int ct = 0; ct < 4; ++ct) {
      f16x8 b = wfrag[(kstep * 8 + colgrp * 4 + ct) * 64 + lane];
      acc[ct] = __builtin_amdgcn_mfma_f32_16x16x32_f16(a, b, acc[ct], 0, 0, 0);
    }
  }
  // D layout: col = lane&15, row = (lane>>4)*4 + reg   [m89-verified]
  #pragma unroll
  for (int ct = 0; ct < 4; ++ct) {
    int col = colgrp * 64 + ct * 16 + (lane & 15);
    #pragma unroll
    for (int reg = 0; reg < 4; ++reg) {
      int r = rowbase + (lane >> 4) * 4 + reg;
      hW16[(size_t)r * DD + col] = __half_as_ushort(__float2half(acc[ct][reg]));
    }
  }
}

// ------- verify MFMA fragment layout on block-tile 0; flag on mismatch -------
__global__ void k_check(const float* __restrict__ x, const float* __restrict__ w,
                        const u16* __restrict__ hW16, u32* __restrict__ flag) {
  int idx = blockIdx.x * 256 + threadIdx.x; // 4096 = 32 rows x 128 cols
  int r = idx >> 7, c = idx & 127;
  const float4* xr = (const float4*)(x + (size_t)r * DD);
  float acc = 0.0f;
  #pragma unroll 8
  for (int k4 = 0; k4 < 32; ++k4) {
    float4 xv = xr[k4];
    int kb = k4 * 4;
    acc += xv.x * w[kb * DD + c] + xv.y * w[(kb + 1) * DD + c]
         + xv.z * w[(kb + 2) * DD + c] + xv.w * w[(kb + 3) * DD + c];
  }
  float got = __half2float(__ushort_as_half(hW16[r * DD + c]));
  if (fabsf(got - acc) > 0.02f) atomicOr(flag, 1u);
}

// ------- scalar fallback GEMM (runs only if MFMA layout check failed) -------
__global__ void k_gemm_fb(const float* __restrict__ x, const float* __restrict__ w,
                          u16* __restrict__ hW16, const u32* __restrict__ flag) {
  if (*flag == 0u) return;
  __shared__ float Wl[DD * DD]; // 64 KiB
  int t = threadIdx.x;
  for (int i = t; i < DD * DD; i += 256) Wl[i] = w[i];
  __syncthreads();
  int base = blockIdx.x * 16;
  int c = t & 127, rh = t >> 7;
  for (int it = 0; it < 8; ++it) {
    int r = base + it * 2 + rh;
    if (r < NN) {
      const float4* xr = (const float4*)(x + (size_t)r * DD);
      float acc = 0.0f;
      #pragma unroll 4
      for (int k4 = 0; k4 < 32; ++k4) {
        float4 xv = xr[k4];
        int kb = k4 * 4;
        acc += xv.x * Wl[kb * DD + c];
        acc += xv.y * Wl[(kb + 1) * DD + c];
        acc += xv.z * Wl[(kb + 2) * DD + c];
        acc += xv.w * Wl[(kb + 3) * DD + c];
      }
      hW16[(size_t)r * DD + c] = __half_as_ushort(__float2half(acc));
    }
  }
}

// ---- gather-aggregate: 2 nodes/wave (32 lanes, 4 dims/lane via uint2) ----
__global__ void k_agg(const u32* __restrict__ hw, const float* __restrict__ dinv32,
                      const u32* __restrict__ offs, const u32* __restrict__ deg,
                      const int* __restrict__ csr, const float* __restrict__ bias,
                      float* __restrict__ hc, u64* __restrict__ key,
                      float* __restrict__ gate) {
  int wid = threadIdx.x >> 6;
  int lane = threadIdx.x & 63;
  int half = lane >> 5;    // which of the wave's 2 nodes
  int l5 = lane & 31;      // handles dims 4*l5 .. 4*l5+3
  int node = blockIdx.x * 8 + wid * 2 + half;
  if (node >= NN) return;
  const uint2* hwp = (const uint2*)hw;
  float di = dinv32[node];
  float a0 = 0.f, a1 = 0.f, a2 = 0.f, a3 = 0.f;
  u32 o = offs[node], cnt = deg[node];
  u32 k = 0;
  for (; k + 4 <= cnt; k += 4) {
    int s0 = csr[o + k], s1 = csr[o + k + 1], s2 = csr[o + k + 2], s3 = csr[o + k + 3];
    float n0 = dinv32[s0] * di, n1 = dinv32[s1] * di;
    float n2 = dinv32[s2] * di, n3 = dinv32[s3] * di;
    uint2 w0 = hwp[(size_t)s0 * 32 + l5];
    uint2 w1 = hwp[(size_t)s1 * 32 + l5];
    uint2 w2 = hwp[(size_t)s2 * 32 + l5];
    uint2 w3 = hwp[(size_t)s3 * 32 + l5];
    float2 p0 = __half22float2(*(__half2*)&w0.x), q0 = __half22float2(*(__half2*)&w0.y);
    float2 p1 = __half22float2(*(__half2*)&w1.x), q1 = __half22float2(*(__half2*)&w1.y);
    float2 p2 = __half22float2(*(__half2*)&w2.x), q2 = __half22float2(*(__half2*)&w2.y);
    float2 p3 = __half22float2(*(__half2*)&w3.x), q3 = __half22float2(*(__half2*)&w3.y);
    a0 += p0.x * n0 + p1.x * n1 + p2.x * n2 + p3.x * n3;
    a1 += p0.y * n0 + p1.y * n1 + p2.y * n2 + p3.y * n3;
    a2 += q0.x * n0 + q1.x * n1 + q2.x * n2 + q3.x * n3;
    a3 += q0.y * n0 + q1.y * n1 + q2.y * n2 + q3.y * n3;
  }
  for (; k < cnt; ++k) {
    int s = csr[o + k];
    float nrm = dinv32[s] * di;
    uint2 wb = hwp[(size_t)s * 32 + l5];
    float2 p = __half22float2(*(__half2*)&wb.x), q = __half22float2(*(__half2*)&wb.y);
    a0 += p.x * nrm; a1 += p.y * nrm; a2 += q.x * nrm; a3 += q.y * nrm;
  }
  float di2 = di * di;
  uint2 wb = hwp[(size_t)node * 32 + l5];
  float2 p = __half22float2(*(__half2*)&wb.x), q = __half22float2(*(__half2*)&wb.y);
  float4 bv = ((const float4*)bias)[l5];
  a0 += p.x * di2 + bv.x;
  a1 += p.y * di2 + bv.y;
  a2 += q.x * di2 + bv.z;
  a3 += q.y * di2 + bv.w;
  float4 out = make_float4(a0, a1, a2, a3);
  ((float4*)hc)[(size_t)node * 32 + l5] = out;
  float ss = a0 * a0 + a1 * a1 + a2 * a2 + a3 * a3;
  #pragma unroll
  for (int off = 16; off > 0; off >>= 1) ss += __shfl_xor(ss, off);
  if (l5 == 0) {
    // approx key: f32 ss bits (monotone in score, ss >= 0);
    // low 17 bits = (0x1FFFF - node) => lower index wins ties
    u32 sb = __float_as_uint(ss);
    key[node] = ((u64)sb << 17) | (u64)(0x1FFFF - node);
    gate[node] = tanhf(sqrtf(ss + 1e-12f));
  }
}

// ---------------- exact bucket-rank (approx keys -> full rank) ----------------
__global__ void k_minmax(const u64* __restrict__ key, u64* __restrict__ meta) {
  __shared__ u64 smn[256], smx[256];
  int t = threadIdx.x; int i = blockIdx.x * 256 + t;
  u64 v = (i < NN) ? key[i] : key[0];
  smn[t] = v; smx[t] = v; __syncthreads();
  for (int s = 128; s > 0; s >>= 1) {
    if (t < s) {
      if (smn[t + s] < smn[t]) smn[t] = smn[t + s];
      if (smx[t + s] > smx[t]) smx[t] = smx[t + s];
    }
    __syncthreads();
  }
  if (t == 0) { atomicMin(&meta[0], smn[0]); atomicMax(&meta[1], smx[0]); }
}

__device__ __forceinline__ u32 bshift(u64 kmin, u64 kmax) {
  u64 range = kmax - kmin;
  int bits = 64 - __clzll(range | 1ull);
  return (u32)(bits > 16 ? bits - 16 : 0); // 2^16 buckets
}

__global__ void k_hist(const u64* __restrict__ key, const u64* __restrict__ meta,
                       u32* __restrict__ barr, u32* __restrict__ bcnt) {
  int i = blockIdx.x * blockDim.x + threadIdx.x;
  if (i >= NN) return;
  u64 kmin = meta[0];
  u32 sh = bshift(kmin, meta[1]);
  u32 b = (u32)((key[i] - kmin) >> sh);
  barr[i] = b;
  atomicAdd(&bcnt[b], 1u);
}

__global__ void k_scan2(u32* __restrict__ bsum, int nb) { // 1 block, 512 thr, nb<=512
  __shared__ u32 buf[2][512];
  int t = threadIdx.x;
  u32 v = (t < nb) ? bsum[t] : 0u;
  int a = 0; buf[0][t] = v; __syncthreads();
  for (int s = 1; s < 512; s <<= 1) {
    buf[1 - a][t] = buf[a][t] + ((t >= s) ? buf[a][t - s] : 0u);
    a = 1 - a; __syncthreads();
  }
  if (t < nb) bsum[t] = buf[a][t] - v; // exclusive
}

__global__ void k_bscan1(const u32* __restrict__ bcnt, u32* __restrict__ bsum2) {
  __shared__ u32 sh[256];
  int t = threadIdx.x; int r = blockIdx.x * 256 + t;
  u32 v = bcnt[NB - 1 - r];
  sh[t] = v; __syncthreads();
  for (int s = 128; s > 0; s >>= 1) { if (t < s) sh[t] += sh[t + s]; __syncthreads(); }
  if (t == 0) bsum2[blockIdx.x] = sh[0];
}

__global__ void k_bscan3(const u32* __restrict__ bcnt, const u32* __restrict__ bsum2,
                         u32* __restrict__ base, u32* __restrict__ bcur) {
  __shared__ u32 buf[2][256];
  int t = threadIdx.x; int r = blockIdx.x * 256 + t;
  int b = NB - 1 - r;
  u32 v = bcnt[b];
  int a = 0; buf[0][t] = v; __syncthreads();
  for (int s = 1; s < 256; s <<= 1) {
    buf[1 - a][t] = buf[a][t] + ((t >= s) ? buf[a][t - s] : 0u);
    a = 1 - a; __syncthreads();
  }
  u32 bs = buf[a][t] - v + bsum2[blockIdx.x]; // suffix-exclusive
  base[b] = bs;
  bcur[b] = NN - bs - v;
}

__global__ void k_bscatter(const u32* __restrict__ barr, u32* __restrict__ bcur,
                           u32* __restrict__ blist) {
  int i = blockIdx.x * blockDim.x + threadIdx.x;
  if (i >= NN) return;
  u32 p = atomicAdd(&bcur[barr[i]], 1u);
  blist[p] = (u32)i;
}

// rank + in-band selection fused
__global__ void k_rank2(const u64* __restrict__ key, const u32* __restrict__ barr,
                        const u32* __restrict__ bcnt, const u32* __restrict__ base,
                        const u32* __restrict__ blist, int* __restrict__ arank,
                        u32* __restrict__ bandNode) {
  int i = blockIdx.x * blockDim.x + threadIdx.x;
  if (i >= NN) return;
  u32 b = barr[i];
  u64 ki = key[i];
  u32 bs = base[b], cnt = bcnt[b];
  u32 off = NN - bs - cnt;
  u32 gt = 0;
  for (u32 j = 0; j < cnt; ++j) gt += (key[blist[off + j]] > ki) ? 1u : 0u;
  int r = (int)(bs + gt);
  arank[i] = r; // full approx rank (a permutation of 0..NN-1)
  int rb = r - (KK - BB);
  if (rb >= 0 && rb < 2 * BB) bandNode[rb] = (u32)i;
}

// ---------------- exact band repair ----------------
// exact f64 rescore via linearity: a = (sum_s wgt_s * x_s) @ W + bias
__global__ void k_bscore(const u32* __restrict__ bandNode,
                         const float* __restrict__ x, const float* __restrict__ w,
                         const double* __restrict__ dinv64,
                         const u32* __restrict__ offs, const u32* __restrict__ deg,
                         const int* __restrict__ csr, const float* __restrict__ bias,
                         u64* __restrict__ ekey) {
  __shared__ double zsh[4][DD]; // 4 KiB
  int wid = threadIdx.x >> 6;
  int lane = threadIdx.x & 63;
  int slot = blockIdx.x * 4 + wid;
  int node = (int)bandNode[slot];
  double di = dinv64[node];
  double z0 = 0.0, z1 = 0.0;
  u32 o = offs[node], cnt = deg[node];
  for (u32 k = 0; k <= cnt; ++k) { // last iter = self row
    int s = (k < cnt) ? csr[o + k] : node;
    double wgt = (k < cnt) ? (dinv64[s] * di) : (di * di);
    float2 xv = ((const float2*)x)[(size_t)s * 64 + lane];
    z0 += (double)xv.x * wgt;
    z1 += (double)xv.y * wgt;
  }
  zsh[wid][2 * lane] = z0;
  zsh[wid][2 * lane + 1] = z1;
  __syncthreads();
  float2 bv = ((const float2*)bias)[lane];
  double a0 = (double)bv.x, a1 = (double)bv.y;
  for (int kk = 0; kk < DD; ++kk) {
    double zk = zsh[wid][kk];
    float2 wv = ((const float2*)w)[kk * 64 + lane];
    a0 += zk * (double)wv.x;
    a1 += zk * (double)wv.y;
  }
  double ss = a0 * a0 + a1 * a1;
  #pragma unroll
  for (int off = 32; off > 0; off >>= 1) ss += __shfl_xor(ss, off);
  if (lane == 0) {
    double sc = sqrt(ss + 1e-12);
    u64 bits = (u64)__double_as_longlong(sc);
    ekey[slot] = (bits & ~0x1FFFFull) | (u64)(0x1FFFF - node);
  }
}

__global__ void k_bandrank(const u64* __restrict__ ekey, u32* __restrict__ brank) {
  __shared__ u64 sk[2 * BB]; // 32 KiB
  int t = threadIdx.x;
  for (int j = t; j < 2 * BB; j += 256) sk[j] = ekey[j];
  __syncthreads();
  int idx = blockIdx.x * 256 + t;
  u64 kk = sk[idx];
  u32 c = 0;
  for (int j = 0; j < 2 * BB; ++j) c += (sk[j] > kk) ? 1u : 0u;
  brank[idx] = c;
}

__global__ void k_pos2(const int* __restrict__ arank, const u32* __restrict__ brank,
                       int* __restrict__ pos) {
  int i = blockIdx.x * blockDim.x + threadIdx.x;
  if (i >= NN) return;
  int r = arank[i];
  int p;
  if (r < KK - BB) p = r;                       // surely kept
  else if (r < KK + BB) {                       // band: exact order decides
    u32 br = brank[r - (KK - BB)];
    p = (br < BB) ? (KK - BB + (int)br) : -1;
  } else p = -1;                                // surely dropped
  pos[i] = p;
}

// ---------------- outputs (f32, bf16-RNE-quantized) ----------------
__global__ void k_xout(const float* __restrict__ hc, const float* __restrict__ gate,
                       const int* __restrict__ pos, float* __restrict__ outx) {
  int id = blockIdx.x * blockDim.x + threadIdx.x;
  if (id >= NN * DD) return;
  int i = id >> 7, d = id & 127;
  int p = pos[i];
  if (p < 0) return;
  float v = hc[(size_t)i * DD + d] * gate[i];
  outx[(size_t)p * DD + d] = bq(v);
}

__global__ void k_edges(const int* __restrict__ ei, const int* __restrict__ pos,
                        float* __restrict__ osrc, float* __restrict__ odst,
                        float* __restrict__ omask) {
  int e = blockIdx.x * blockDim.x + threadIdx.x;
  if (e >= EE) return;
  int ns = pos[ei[e]];
  int nd = pos[ei[EE + e]];
  bool m = (ns >= 0) && (nd >= 0);
  osrc[e] = m ? bq((float)ns) : -1.0f;
  odst[e] = m ? bq((float)nd) : -1.0f;
  omask[e] = m ? 1.0f : 0.0f;
}

// ---------------- driver ----------------
extern "C" void kernel_launch(void* const* d_in, const int* in_sizes, int n_in,
                              void* d_out, int out_size, void* d_ws, size_t ws_size,
                              hipStream_t stream) {
  const float* x    = (const float*)d_in[0];
  const int*   ei   = (const int*)d_in[1];
  const float* w    = (const float*)d_in[2];
  const float* bias = (const float*)d_in[3];
  float* outx = (float*)d_out;
  char* ws = (char*)d_ws;

  size_t off = 0;
  auto alloc = [&](size_t b) -> void* {
    void* p = ws + off; off += (b + 255) & ~(size_t)255; return p;
  };
  u16*    hW16   = (u16*)alloc((size_t)NN * DD * 2);
  float*  hc     = (float*)alloc((size_t)NN * DD * 4);
  double* dinv64 = (double*)alloc((size_t)NN * 8);
  float*  dinv32 = (float*)alloc((size_t)NN * 4);
  float*  gate   = (float*)alloc((size_t)NN * 4);
  u64*    key    = (u64*)alloc((size_t)NN * 8);
  u32*    deg    = (u32*)alloc((size_t)NN * 4);
  u32*    offs   = (u32*)alloc((size_t)NN * 4);
  int*    csr    = (int*)alloc((size_t)EE * 4);
  u32*    ebuf   = (u32*)alloc((size_t)EE * 4);
  u32*    chist  = (u32*)alloc((size_t)NBK * 4);
  u32*    cbase  = (u32*)alloc((size_t)NBK * 4);
  u32*    pbcur  = (u32*)alloc((size_t)NBK * 4);
  int*    arank  = (int*)alloc((size_t)NN * 4);
  int*    pos    = (int*)alloc((size_t)NN * 4);
  u64*    meta   = (u64*)alloc(4 * 8);
  u32*    bcnt   = (u32*)alloc((size_t)NB * 4);
  u32*    base   = (u32*)alloc((size_t)NB * 4);
  u32*    bcur   = (u32*)alloc((size_t)NB * 4);
  u32*    bsum2  = (u32*)alloc(SBLK * 4);
  u32*    barr   = (u32*)alloc((size_t)NN * 4);
  u32*    blist  = (u32*)alloc((size_t)NN * 4);
  u32*    bandNode = (u32*)alloc((size_t)2 * BB * 4);
  u64*    ekey     = (u64*)alloc((size_t)2 * BB * 8);
  u32*    brank    = (u32*)alloc((size_t)2 * BB * 4);
  f16x8*  wfrag    = (f16x8*)alloc((size_t)2048 * 16);
  u32*    mflag    = (u32*)alloc(256);

  k_init<<<256, 256, 0, stream>>>(chist, bcnt, meta, mflag);
  // CSR build: coarse hist -> scan -> 2-pass partition (no global atomic storms)
  k_chist<<<(EE + TILE - 1) / TILE, 256, 0, stream>>>(ei, chist);
  k_cscan<<<1, 512, 0, stream>>>(chist, cbase, pbcur);
  k_part1<<<(EE + TILE - 1) / TILE, 256, 0, stream>>>(ei, pbcur, ebuf);
  k_part2<<<NBK, 256, 0, stream>>>(ebuf, cbase, deg, offs, dinv64, dinv32, csr);
  // GEMM: MFMA main path + layout self-check + scalar fallback
  k_wfrag<<<8, 256, 0, stream>>>(w, wfrag);
  k_gemm_mfma<<<NN / 32, 256, 0, stream>>>(x, wfrag, hW16);
  k_check<<<16, 256, 0, stream>>>(x, w, hW16, mflag);
  k_gemm_fb<<<(NN + 15) / 16, 256, 0, stream>>>(x, w, hW16, mflag);
  k_agg<<<(NN + 7) / 8, 256, 0, stream>>>((const u32*)hW16, dinv32, offs, deg, csr,
                                          bias, hc, key, gate);
  k_minmax<<<NBLK, 256, 0, stream>>>(key, meta);
  k_hist<<<(NN + 255) / 256, 256, 0, stream>>>(key, meta, barr, bcnt);
  k_bscan1<<<SBLK, 256, 0, stream>>>(bcnt, bsum2);
  k_scan2<<<1, 512, 0, stream>>>(bsum2, SBLK);
  k_bscan3<<<SBLK, 256, 0, stream>>>(bcnt, bsum2, base, bcur);
  k_bscatter<<<(NN + 255) / 256, 256, 0, stream>>>(barr, bcur, blist);
  k_rank2<<<(NN + 255) / 256, 256, 0, stream>>>(key, barr, bcnt, base, blist, arank,
                                                bandNode);
  // exact band repair (f64 truth via linearity)
  k_bscore<<<(2 * BB) / 4, 256, 0, stream>>>(bandNode, x, w, dinv64, offs, deg, csr,
                                             bias, ekey);
  k_bandrank<<<(2 * BB) / 256, 256, 0, stream>>>(ekey, brank);
  k_pos2<<<(NN + 255) / 256, 256, 0, stream>>>(arank, brank, pos);
  k_xout<<<(NN * DD + 255) / 256, 256, 0, stream>>>(hc, gate, pos, outx);
  float* oei = outx + (size_t)KK * DD;
  k_edges<<<(EE + 255) / 256, 256, 0, stream>>>(ei, pos, oei, oei + EE, oei + 2 * (size_t)EE);
}